// Round 7
// baseline (830.278 us; speedup 1.0000x reference)
//
#include <hip/hip_runtime.h>
#include <hip/hip_bf16.h>
#include <math.h>

typedef __hip_bfloat16 bf16;
typedef unsigned short u16;

#define NUSR 50000
#define NENT 100000
#define CC   64
#define EE   1500000
#define NNZI 1000000
#define NF_  4
#define R1_  15
#define R2_  47
#define NSH  8          // counter shards (XCD-count heuristic)

__device__ __forceinline__ float b2f(bf16 x){ return __bfloat162float(x); }
__device__ __forceinline__ bf16  f2b(float x){ return __float2bfloat16(x); }
__device__ __forceinline__ float fin(float x){ return (x==x && fabsf(x) < 1e30f) ? x : 0.f; }

// RNE float->bf16 bits (matches __float2bfloat16 for finite inputs)
__device__ __forceinline__ unsigned bf16bits(float x){
    unsigned b = __float_as_uint(x);
    return (b + 0x7FFFu + ((b >> 16) & 1u)) >> 16;
}
__device__ __forceinline__ float pk_lo(unsigned p){ return __uint_as_float(p << 16); }
__device__ __forceinline__ float pk_hi(unsigned p){ return __uint_as_float(p & 0xFFFF0000u); }

// wave-uniform hoist to SGPR (full-wave call sites only)
__device__ __forceinline__ unsigned rflu(unsigned x){ return (unsigned)__builtin_amdgcn_readfirstlane((int)x); }
// extract lane kk (wave-uniform kk) of a VGPR holding 64 row-cached CSR words
__device__ __forceinline__ unsigned rdl(unsigned v, int kk){ return (unsigned)__builtin_amdgcn_readlane((int)v, kk); }

__device__ __forceinline__ float ldv(const float* p, long long i){ return p[i]; }
__device__ __forceinline__ float ldv(const bf16*  p, long long i){ return b2f(p[i]); }

struct LatArgs {
    const float *lin, *W1, *b1, *W2, *b2, *Wua, *bua, *Wwa, *bwa, *wt;
    float *lat, *nlat, *P2, *q2;
    int R;
};

// ---------------------------------------------------------------- histogram + per-element rank + (fused) fp32->bf16 conv
// Counters sharded 8-way by blockIdx&7 (round-robin XCD heuristic).
// Third block-role converts the entity table to bf16 (independent of hist).
__global__ void k_hist(const int* __restrict__ head, const int* __restrict__ irows,
                       int* deg8_e, int* deg8_u,
                       u16* __restrict__ rank_e, u16* __restrict__ rank_u,
                       const float* __restrict__ esrc, bf16* __restrict__ ebf){
    int i = blockIdx.x*256 + threadIdx.x;
    int shard = blockIdx.x & (NSH-1);
    if (i < EE){
        int h = head[i];
        int r = ((unsigned)h < NENT) ? atomicAdd(&deg8_e[shard*NENT + h], 1) : 0;
        rank_e[i] = (u16)((r & 8191) | (shard << 13));
    } else if (i < EE + NNZI){
        int j = i - EE;
        int rr = irows[j];
        int r = ((unsigned)rr < NUSR) ? atomicAdd(&deg8_u[shard*NUSR + rr], 1) : 0;
        rank_u[j] = (u16)((r & 8191) | (shard << 13));
    } else if (ebf){
        long long j = (long long)(i - (EE + NNZI)) * 4;
        if (j < (long long)NENT*CC){
            const float4 v = *(const float4*)(esrc + j);
            u16* o = (u16*)ebf + j;
            o[0] = (u16)bf16bits(v.x); o[1] = (u16)bf16bits(v.y);
            o[2] = (u16)bf16bits(v.z); o[3] = (u16)bf16bits(v.w);
        }
    }
}

// ---------------------------------------------------------------- row bases via wave-scan
// Also converts the per-shard counts into in-place exclusive prefixes (xoff).
__global__ void k_base2(int* deg8_e, int* deg8_u,
                        unsigned* rsdeg_e, unsigned* rsdeg_u, int* ctrs){
    int i = blockIdx.x*256 + threadIdx.x;
    int lane = threadIdx.x & 63;
    { // entities
        int d = 0;
        if (i < NENT){
            int tot = 0;
            #pragma unroll
            for (int c = 0; c < NSH; c++){
                int v = deg8_e[c*NENT + i];
                deg8_e[c*NENT + i] = tot;          // exclusive prefix (xoff)
                tot += v;
            }
            d = tot;
        }
        int incl = d;
        for (int off = 1; off < 64; off <<= 1){
            int v = __shfl_up(incl, off, 64);
            if (lane >= off) incl += v;
        }
        int tot = __shfl(incl, 63, 64);
        int base = 0;
        if (lane == 63) base = atomicAdd(&ctrs[0], tot);
        base = __shfl(base, 63, 64);
        if (i < NENT){
            unsigned rs = (unsigned)(base + incl - d);
            int dc = d < 2047 ? d : 2047;
            rsdeg_e[i] = (rs & 0x1FFFFFu) | ((unsigned)dc << 21);
        }
    }
    { // users
        int d = 0;
        if (i < NUSR){
            int tot = 0;
            #pragma unroll
            for (int c = 0; c < NSH; c++){
                int v = deg8_u[c*NUSR + i];
                deg8_u[c*NUSR + i] = tot;
                tot += v;
            }
            d = tot;
        }
        int incl = d;
        for (int off = 1; off < 64; off <<= 1){
            int v = __shfl_up(incl, off, 64);
            if (lane >= off) incl += v;
        }
        int tot = __shfl(incl, 63, 64);
        int base = 0;
        if (lane == 63) base = atomicAdd(&ctrs[1], tot);
        base = __shfl(base, 63, 64);
        if (i < NUSR){
            unsigned rs = (unsigned)(base + incl - d);
            int dc = d < 4095 ? d : 4095;
            rsdeg_u[i] = (rs & 0xFFFFFu) | ((unsigned)dc << 20);
        }
    }
}

// ---------------------------------------------------------------- CSR scatter (plain stores; no atomics)
__global__ void k_scatter(const int* __restrict__ head, const int* __restrict__ tail,
                          const int* __restrict__ etype, const int* __restrict__ cate,
                          const int* __restrict__ irows, const int* __restrict__ icols,
                          const float* __restrict__ ivals,
                          const u16* __restrict__ rank_e, const u16* __restrict__ rank_u,
                          const int* __restrict__ xoff_e, const int* __restrict__ xoff_u,
                          const unsigned* __restrict__ rsdeg_e, const unsigned* __restrict__ rsdeg_u,
                          unsigned* __restrict__ epk, unsigned* __restrict__ upk){
    int i = blockIdx.x*256 + threadIdx.x;
    if (i < EE){
        int h = head[i]; if ((unsigned)h >= NENT) return;
        unsigned tu = (unsigned)tail[i]; if (tu >= NENT) tu = 0;
        unsigned rk = rank_e[i];
        int shard = rk >> 13, r = rk & 8191;
        int slot = (int)(rsdeg_e[h] & 0x1FFFFFu) + xoff_e[shard*NENT + h] + r;
        unsigned ty = (unsigned)(etype[i] - 1) & 15u;
        unsigned cd = (unsigned)(cate[tu]  - 1) & 31u;
        if ((unsigned)slot < EE)
            epk[slot] = tu | (ty << 17) | (cd << 21);
    } else {
        int j = i - EE;
        if (j < NNZI){
            int rr = irows[j]; if ((unsigned)rr >= NUSR) return;
            unsigned c = (unsigned)icols[j]; if (c >= NENT) c = 0;
            unsigned rk = rank_u[j];
            int shard = rk >> 13, r = rk & 8191;
            int slot = (int)(rsdeg_u[rr] & 0xFFFFFu) + xoff_u[shard*NUSR + rr] + r;
            unsigned bits = __float_as_uint(ivals[j]);
            unsigned rb = bits + 0x7FFFu + ((bits >> 16) & 1u);   // RNE to bf16
            unsigned vb = (rb >> 16) & 0x7FFFu;                    // sign always 0
            if ((unsigned)slot < NNZI)
                upk[slot] = c | (vb << 17);
        }
    }
}

// ---------------------------------------------------------------- latent path: both branches, LDS-staged
__global__ void k_lat2(LatArgs A0, LatArgs A1){
    LatArgs a = (blockIdx.x == 0) ? A0 : A1;
    const int R = a.R;
    __shared__ float sW1[64*64], sW2[64*64];
    __shared__ float swt[R2_*64], wp[R2_*64];
    __shared__ float lf[NF_*64], lp1[NF_*64], lp2[NF_*64];
    __shared__ float Praw[64*NF_], qv[NF_];
    __shared__ float srp[NF_*R2_], zz[NF_*R2_];
    __shared__ float latls[NF_*64], norms[NF_];
    int t = threadIdx.x;

    for (int idx = t; idx < 64*64; idx += 256){ sW1[idx] = a.W1[idx]; sW2[idx] = a.W2[idx]; }
    for (int idx = t; idx < R*64; idx += 256) swt[idx] = a.wt[idx];
    lf[t] = fin(a.lin[t]);
    __syncthreads();

    { // l' = l@W1+b1 ; l2' = l@W2+b2
        int f = t >> 6, k = t & 63;
        float s1 = a.b1[k], s2 = a.b2[k];
        for (int c = 0; c < 64; c++){
            float lv = lf[f*64+c];
            s1 += lv * sW1[c*64+k];
            s2 += lv * sW2[c*64+k];
        }
        lp1[t] = s1; lp2[t] = s2;
    }
    __syncthreads();

    { // Praw[c][f] = sum_k W1[c,k] * l'[f,k]
        int c = t >> 2, f = t & 3;
        float s = 0.f;
        for (int k = 0; k < 64; k++) s += sW1[c*64+k] * lp1[f*64+k];
        Praw[c*4+f] = s;
    }
    if (t < NF_){
        float s = 0.f;
        for (int k = 0; k < 64; k++) s += a.b1[k] * lp1[t*64+k];
        qv[t] = s;
    }
    __syncthreads();

    { // P2[g*64+c] = sum_f Praw[c][f]*Wua[f][g]
        int g = t >> 6, c = t & 63;
        float s = 0.f;
        for (int f = 0; f < NF_; f++) s += Praw[c*4+f] * a.Wua[f*4+g];
        a.P2[g*64+c] = s;
    }
    if (t < NF_){
        float s = a.bua[t];
        for (int f = 0; f < NF_; f++) s += qv[f] * a.Wua[f*4+t];
        a.q2[t] = s;
    }
    // w' = weight@W2 + b2
    for (int idx = t; idx < R*64; idx += 256){
        int r = idx >> 6, k = idx & 63;
        float s = a.b2[k];
        for (int c = 0; c < 64; c++) s += swt[r*64+c] * sW2[c*64+k];
        wp[idx] = s;
    }
    __syncthreads();

    if (t < NF_*R){ // srp[f][r] = dot(l2'[f], w'[r])
        int f = t / R, r = t % R;
        float s = 0.f;
        for (int k = 0; k < 64; k++) s += lp2[f*64+k] * wp[r*64+k];
        srp[f*R2_ + r] = s;
    }
    __syncthreads();

    if (t < NF_*R){ // zz = leaky(srp @ Wwa + bwa)
        int f = t / R, ss = t % R;
        float v = a.bwa[ss];
        for (int r = 0; r < R; r++) v += srp[f*R2_ + r] * a.Wwa[r*R + ss];
        zz[f*R2_ + ss] = (v > 0.f) ? v : 0.2f*v;
    }
    __syncthreads();

    if (t < NF_){ // row softmax over R
        float m = -1e30f;
        for (int r = 0; r < R; r++) m = fmaxf(m, zz[t*R2_ + r]);
        float sum = 0.f;
        for (int r = 0; r < R; r++){ float e = expf(zz[t*R2_ + r] - m); zz[t*R2_ + r] = e; sum += e; }
        float inv = 1.f / sum;
        for (int r = 0; r < R; r++) zz[t*R2_ + r] *= inv;
    }
    __syncthreads();

    { // lat_new[f][c] = soft[f] @ weight
        int f = t >> 6, c = t & 63;
        float s = 0.f;
        for (int r = 0; r < R; r++) s += zz[f*R2_ + r] * swt[r*64 + c];
        latls[t] = s; a.lat[t] = s;
    }
    __syncthreads();
    if (t < NF_){
        float s = 0.f;
        for (int c = 0; c < 64; c++){ float v = latls[t*64+c]; s += v*v; }
        norms[t] = fmaxf(sqrtf(s), 1e-12f);
    }
    __syncthreads();
    a.nlat[t] = latls[t] / norms[t >> 6];
}

// ---------------------------------------------------------------- entity agg core (tier B, unchanged)
template<typename SRC>
__device__ __forceinline__ float ent_row(const SRC* __restrict__ e_src, const float* wl,
                                         const unsigned* __restrict__ epk,
                                         unsigned rd, int use_d, int lane){
    rd = rflu(rd);
    int s = (int)(rd & 0x1FFFFFu);
    int deg = (int)(rd >> 21);
    int e_ = s + deg;
    float acc = 0.f;
    int k = s;
    for (; k + 4 <= e_; k += 4){
        unsigned p0 = rflu(epk[k]), p1 = rflu(epk[k+1]), p2 = rflu(epk[k+2]), p3 = rflu(epk[k+3]);
        unsigned t0 = p0 & 0x1FFFFu; t0 = t0 < NENT ? t0 : 0u;
        unsigned t1 = p1 & 0x1FFFFu; t1 = t1 < NENT ? t1 : 0u;
        unsigned t2 = p2 & 0x1FFFFu; t2 = t2 < NENT ? t2 : 0u;
        unsigned t3 = p3 & 0x1FFFFu; t3 = t3 < NENT ? t3 : 0u;
        float g0 = ldv(e_src, (long long)t0*64 + lane);
        float g1 = ldv(e_src, (long long)t1*64 + lane);
        float g2 = ldv(e_src, (long long)t2*64 + lane);
        float g3 = ldv(e_src, (long long)t3*64 + lane);
        int w0 = use_d ? (int)((p0 >> 21) & 31u) : (int)((p0 >> 17) & 15u);
        int w1 = use_d ? (int)((p1 >> 21) & 31u) : (int)((p1 >> 17) & 15u);
        int w2 = use_d ? (int)((p2 >> 21) & 31u) : (int)((p2 >> 17) & 15u);
        int w3 = use_d ? (int)((p3 >> 21) & 31u) : (int)((p3 >> 17) & 15u);
        acc += g0*wl[w0*64+lane] + g1*wl[w1*64+lane] + g2*wl[w2*64+lane] + g3*wl[w3*64+lane];
    }
    for (; k < e_; k++){
        unsigned p = rflu(epk[k]);
        unsigned ti = p & 0x1FFFFu; ti = ti < NENT ? ti : 0u;
        int wi = use_d ? (int)((p >> 21) & 31u) : (int)((p >> 17) & 15u);
        acc += ldv(e_src, (long long)ti*64 + lane) * wl[wi*64+lane];
    }
    float ea = fin(acc) / fmaxf((float)deg, 1.f);
    float sq = ea*ea;
    for (int m = 1; m < 64; m <<= 1) sq += __shfl_xor(sq, m, 64);
    float nrm = fmaxf(sqrtf(fin(sq)), 1e-12f);
    return ea / nrm;
}

// tier B iter-0: fp32 src -> bf16 ws
__global__ __launch_bounds__(256) void k_ent0(const float* __restrict__ e_src,
                                              const float* __restrict__ wtab, int R, int use_d,
                                              const unsigned* __restrict__ rsdeg_e,
                                              const unsigned* __restrict__ epk,
                                              bf16* dst){
    __shared__ float wl[R2_*64];
    int t = threadIdx.x;
    for (int idx = t; idx < R2_*64; idx += 256)
        wl[idx] = (idx < R*64) ? wtab[idx] : 0.f;
    __syncthreads();
    int ent = blockIdx.x*4 + (t >> 6);
    int lane = t & 63;
    if (ent >= NENT) return;
    float v = ent_row(e_src, wl, epk, rsdeg_e[ent], use_d, lane);
    dst[(long long)ent*64 + lane] = f2b(v);
}

// tier B iter-1 fused residual
__global__ __launch_bounds__(256) void k_ent1f(const bf16* __restrict__ e_src,
                                               const float* __restrict__ base_emb,
                                               const float* __restrict__ wtab, int R, int use_d,
                                               const unsigned* __restrict__ rsdeg_e,
                                               const unsigned* __restrict__ epk,
                                               float* dst){
    __shared__ float wl[R2_*64];
    int t = threadIdx.x;
    for (int idx = t; idx < R2_*64; idx += 256)
        wl[idx] = (idx < R*64) ? wtab[idx] : 0.f;
    __syncthreads();
    int ent = blockIdx.x*4 + (t >> 6);
    int lane = t & 63;
    if (ent >= NENT) return;
    float v = ent_row(e_src, wl, epk, rsdeg_e[ent], use_d, lane);
    long long ix = (long long)ent*64 + lane;
    dst[ix] = base_emb[ix] + b2f(e_src[ix]) + v;
}

// ---------------------------------------------------------------- user agg pieces (tier B, unchanged)
template<typename ESRC>
__device__ __forceinline__ float usr_gather(const ESRC* __restrict__ e_src,
                                            const unsigned* __restrict__ upk,
                                            unsigned rd, int lane){
    rd = rflu(rd);
    int s = (int)(rd & 0xFFFFFu);
    int e_ = s + (int)(rd >> 20);
    float acc = 0.f;
    int k = s;
    for (; k + 4 <= e_; k += 4){
        unsigned p0 = rflu(upk[k]), p1 = rflu(upk[k+1]), p2 = rflu(upk[k+2]), p3 = rflu(upk[k+3]);
        unsigned c0 = p0 & 0x1FFFFu; c0 = c0 < NENT ? c0 : 0u;
        unsigned c1 = p1 & 0x1FFFFu; c1 = c1 < NENT ? c1 : 0u;
        unsigned c2 = p2 & 0x1FFFFu; c2 = c2 < NENT ? c2 : 0u;
        unsigned c3 = p3 & 0x1FFFFu; c3 = c3 < NENT ? c3 : 0u;
        float v0 = __uint_as_float(((p0 >> 17) & 0x7FFFu) << 16);
        float v1 = __uint_as_float(((p1 >> 17) & 0x7FFFu) << 16);
        float v2 = __uint_as_float(((p2 >> 17) & 0x7FFFu) << 16);
        float v3 = __uint_as_float(((p3 >> 17) & 0x7FFFu) << 16);
        acc += v0*ldv(e_src,(long long)c0*64+lane) + v1*ldv(e_src,(long long)c1*64+lane)
             + v2*ldv(e_src,(long long)c2*64+lane) + v3*ldv(e_src,(long long)c3*64+lane);
    }
    for (; k < e_; k++){
        unsigned p = rflu(upk[k]);
        unsigned c = p & 0x1FFFFu; c = c < NENT ? c : 0u;
        float v = __uint_as_float(((p >> 17) & 0x7FFFu) << 16);
        acc += v * ldv(e_src, (long long)c*64 + lane);
    }
    return fin(acc);
}

__device__ __forceinline__ float usr_epi(float acc, float x,
                                         const float* P2l, const float* latl, const float* q2l,
                                         int lane){
    float s0 = x*P2l[lane], s1 = x*P2l[64+lane], s2 = x*P2l[128+lane], s3 = x*P2l[192+lane];
    for (int m = 1; m < 64; m <<= 1){
        s0 += __shfl_xor(s0, m, 64);
        s1 += __shfl_xor(s1, m, 64);
        s2 += __shfl_xor(s2, m, 64);
        s3 += __shfl_xor(s3, m, 64);
    }
    s0 += q2l[0]; s1 += q2l[1]; s2 += q2l[2]; s3 += q2l[3];
    s0 = (s0 > 0.f) ? s0 : 0.2f*s0;
    s1 = (s1 > 0.f) ? s1 : 0.2f*s1;
    s2 = (s2 > 0.f) ? s2 : 0.2f*s2;
    s3 = (s3 > 0.f) ? s3 : 0.2f*s3;
    float mx = fmaxf(fmaxf(s0, s1), fmaxf(s2, s3));
    float e0 = expf(s0-mx), e1 = expf(s1-mx), e2 = expf(s2-mx), e3 = expf(s3-mx);
    float inv = 1.f / (e0+e1+e2+e3);
    float mix = fin((e0*latl[lane] + e1*latl[64+lane] + e2*latl[128+lane] + e3*latl[192+lane]) * inv);
    float ua = acc * (1.f + mix);
    float sq = ua*ua;
    for (int m = 1; m < 64; m <<= 1) sq += __shfl_xor(sq, m, 64);
    float nrm = fmaxf(sqrtf(fin(sq)), 1e-12f);
    return ua / nrm;
}

// tier B iter-0 user
__global__ __launch_bounds__(256) void k_usr0(const float* __restrict__ u_src,
                                              const float* __restrict__ e_src,
                                              const unsigned* __restrict__ rsdeg_u,
                                              const unsigned* __restrict__ upk,
                                              const float* __restrict__ P2,
                                              const float* __restrict__ q2,
                                              const float* __restrict__ lat_new,
                                              float* dst){
    __shared__ float P2l[NF_*64], latl[NF_*64], q2l[NF_];
    int t = threadIdx.x;
    P2l[t] = fin(P2[t]); latl[t] = fin(lat_new[t]);
    if (t < NF_) q2l[t] = fin(q2[t]);
    __syncthreads();
    int u = blockIdx.x*4 + (t >> 6);
    int lane = t & 63;
    if (u >= NUSR) return;
    float acc = usr_gather(e_src, upk, rsdeg_u[u], lane);
    float x = u_src[(long long)u*64 + lane];
    dst[(long long)u*64 + lane] = usr_epi(acc, x, P2l, latl, q2l, lane);
}

// tier B iter-1 user
__global__ __launch_bounds__(256) void k_usr1f(float* u_io,
                                               const bf16* __restrict__ e_src,
                                               const float* __restrict__ base_emb,
                                               const unsigned* __restrict__ rsdeg_u,
                                               const unsigned* __restrict__ upk,
                                               const float* __restrict__ P2,
                                               const float* __restrict__ q2,
                                               const float* __restrict__ lat_new){
    __shared__ float P2l[NF_*64], latl[NF_*64], q2l[NF_];
    int t = threadIdx.x;
    P2l[t] = fin(P2[t]); latl[t] = fin(lat_new[t]);
    if (t < NF_) q2l[t] = fin(q2[t]);
    __syncthreads();
    int u = blockIdx.x*4 + (t >> 6);
    int lane = t & 63;
    if (u >= NUSR) return;
    float acc = usr_gather(e_src, upk, rsdeg_u[u], lane);
    long long ix = (long long)u*64 + lane;
    float x = u_io[ix];
    float v = usr_epi(acc, x, P2l, latl, q2l, lane);
    u_io[ix] = base_emb[ix] + x + v;
}

// ---------------------------------------------------------------- tier A fused iter-0 (row-cached CSR words):
// blocks [0,GE): entity gather -> packed eA2; blocks [GE,GE+GU): user gather -> ou_c/ou_d.
// Row-cache: one coalesced load pulls 64 edge-words into a VGPR; readlane(kk) extracts
// each word as an SGPR (uniform kk) -> per-edge VMEM halves and gathers issue back-to-back.
#define GE_ ((NENT+3)/4)
#define GU_ ((NUSR+3)/4)
__global__ __launch_bounds__(256) void k_it0(const bf16* __restrict__ ebf,
                                             const float* __restrict__ wt_c,
                                             const float* __restrict__ wt_d,
                                             const unsigned* __restrict__ rsdeg_e,
                                             const unsigned* __restrict__ epk,
                                             unsigned* __restrict__ eA2,
                                             const float* __restrict__ u_src,
                                             const unsigned* __restrict__ rsdeg_u,
                                             const unsigned* __restrict__ upk,
                                             const float* __restrict__ P2c,
                                             const float* __restrict__ q2c,
                                             const float* __restrict__ latc,
                                             const float* __restrict__ P2d,
                                             const float* __restrict__ q2d,
                                             const float* __restrict__ latd,
                                             float* __restrict__ dst_c,
                                             float* __restrict__ dst_d){
    __shared__ float sm[(R1_+R2_)*64];      // 15872 B, shared by both roles
    int t = threadIdx.x;
    int lane = t & 63;
    if (blockIdx.x < GE_){
        float* wlc = sm;                    // R1_*64
        float* wld = sm + R1_*64;           // R2_*64
        for (int idx = t; idx < R1_*64; idx += 256) wlc[idx] = wt_c[idx];
        for (int idx = t; idx < R2_*64; idx += 256) wld[idx] = wt_d[idx];
        __syncthreads();
        int ent = blockIdx.x*4 + (t >> 6);
        if (ent >= NENT) return;
        unsigned rd = rflu(rsdeg_e[ent]);
        int s = (int)(rd & 0x1FFFFFu);
        int deg = (int)(rd >> 21);
        int e_ = s + deg;
        float ac = 0.f, ad = 0.f;
        for (int kb = s; kb < e_; kb += 64){
            int gi2 = kb + lane;
            unsigned pkv = epk[gi2 < e_ ? gi2 : s];
            int rem = e_ - kb; if (rem > 64) rem = 64;
            int kk = 0;
            for (; kk + 8 <= rem; kk += 8){
                unsigned p0 = rdl(pkv, kk),   p1 = rdl(pkv, kk+1), p2 = rdl(pkv, kk+2), p3 = rdl(pkv, kk+3);
                unsigned p4 = rdl(pkv, kk+4), p5 = rdl(pkv, kk+5), p6 = rdl(pkv, kk+6), p7 = rdl(pkv, kk+7);
                unsigned t0 = p0 & 0x1FFFFu; t0 = t0 < NENT ? t0 : 0u;
                unsigned t1 = p1 & 0x1FFFFu; t1 = t1 < NENT ? t1 : 0u;
                unsigned t2 = p2 & 0x1FFFFu; t2 = t2 < NENT ? t2 : 0u;
                unsigned t3 = p3 & 0x1FFFFu; t3 = t3 < NENT ? t3 : 0u;
                unsigned t4 = p4 & 0x1FFFFu; t4 = t4 < NENT ? t4 : 0u;
                unsigned t5 = p5 & 0x1FFFFu; t5 = t5 < NENT ? t5 : 0u;
                unsigned t6 = p6 & 0x1FFFFu; t6 = t6 < NENT ? t6 : 0u;
                unsigned t7 = p7 & 0x1FFFFu; t7 = t7 < NENT ? t7 : 0u;
                float g0 = b2f(ebf[(long long)t0*64 + lane]);
                float g1 = b2f(ebf[(long long)t1*64 + lane]);
                float g2 = b2f(ebf[(long long)t2*64 + lane]);
                float g3 = b2f(ebf[(long long)t3*64 + lane]);
                float g4 = b2f(ebf[(long long)t4*64 + lane]);
                float g5 = b2f(ebf[(long long)t5*64 + lane]);
                float g6 = b2f(ebf[(long long)t6*64 + lane]);
                float g7 = b2f(ebf[(long long)t7*64 + lane]);
                ac += g0*wlc[((p0>>17)&15u)*64+lane] + g1*wlc[((p1>>17)&15u)*64+lane]
                    + g2*wlc[((p2>>17)&15u)*64+lane] + g3*wlc[((p3>>17)&15u)*64+lane]
                    + g4*wlc[((p4>>17)&15u)*64+lane] + g5*wlc[((p5>>17)&15u)*64+lane]
                    + g6*wlc[((p6>>17)&15u)*64+lane] + g7*wlc[((p7>>17)&15u)*64+lane];
                ad += g0*wld[((p0>>21)&31u)*64+lane] + g1*wld[((p1>>21)&31u)*64+lane]
                    + g2*wld[((p2>>21)&31u)*64+lane] + g3*wld[((p3>>21)&31u)*64+lane]
                    + g4*wld[((p4>>21)&31u)*64+lane] + g5*wld[((p5>>21)&31u)*64+lane]
                    + g6*wld[((p6>>21)&31u)*64+lane] + g7*wld[((p7>>21)&31u)*64+lane];
            }
            for (; kk < rem; kk++){
                unsigned p = rdl(pkv, kk);
                unsigned ti = p & 0x1FFFFu; ti = ti < NENT ? ti : 0u;
                float g = b2f(ebf[(long long)ti*64 + lane]);
                ac += g*wlc[((p>>17)&15u)*64+lane];
                ad += g*wld[((p>>21)&31u)*64+lane];
            }
        }
        float inv_deg = 1.f / fmaxf((float)deg, 1.f);
        float ec = fin(ac) * inv_deg, ed = fin(ad) * inv_deg;
        float sc = ec*ec, sd = ed*ed;
        for (int m = 1; m < 64; m <<= 1){
            sc += __shfl_xor(sc, m, 64);
            sd += __shfl_xor(sd, m, 64);
        }
        float vc = ec / fmaxf(sqrtf(fin(sc)), 1e-12f);
        float vd = ed / fmaxf(sqrtf(fin(sd)), 1e-12f);
        eA2[(long long)ent*64 + lane] = bf16bits(vc) | (bf16bits(vd) << 16);
    } else {
        float* P2lc = sm;            // 256
        float* latlc = sm + 256;     // 256
        float* P2ld = sm + 512;      // 256
        float* latld = sm + 768;     // 256
        float* q2lc = sm + 1024;     // 4
        float* q2ld = sm + 1032;     // 4
        P2lc[t] = fin(P2c[t]); latlc[t] = fin(latc[t]);
        P2ld[t] = fin(P2d[t]); latld[t] = fin(latd[t]);
        if (t < NF_){ q2lc[t] = fin(q2c[t]); q2ld[t] = fin(q2d[t]); }
        __syncthreads();
        int u = (blockIdx.x - GE_)*4 + (t >> 6);
        if (u >= NUSR) return;
        unsigned rd = rflu(rsdeg_u[u]);
        int s = (int)(rd & 0xFFFFFu);
        int e_ = s + (int)(rd >> 20);
        float acc = 0.f;
        for (int kb = s; kb < e_; kb += 64){
            int gi2 = kb + lane;
            unsigned pkv = upk[gi2 < e_ ? gi2 : s];
            int rem = e_ - kb; if (rem > 64) rem = 64;
            int kk = 0;
            for (; kk + 8 <= rem; kk += 8){
                unsigned p0 = rdl(pkv, kk),   p1 = rdl(pkv, kk+1), p2 = rdl(pkv, kk+2), p3 = rdl(pkv, kk+3);
                unsigned p4 = rdl(pkv, kk+4), p5 = rdl(pkv, kk+5), p6 = rdl(pkv, kk+6), p7 = rdl(pkv, kk+7);
                unsigned c0 = p0 & 0x1FFFFu; c0 = c0 < NENT ? c0 : 0u;
                unsigned c1 = p1 & 0x1FFFFu; c1 = c1 < NENT ? c1 : 0u;
                unsigned c2 = p2 & 0x1FFFFu; c2 = c2 < NENT ? c2 : 0u;
                unsigned c3 = p3 & 0x1FFFFu; c3 = c3 < NENT ? c3 : 0u;
                unsigned c4 = p4 & 0x1FFFFu; c4 = c4 < NENT ? c4 : 0u;
                unsigned c5 = p5 & 0x1FFFFu; c5 = c5 < NENT ? c5 : 0u;
                unsigned c6 = p6 & 0x1FFFFu; c6 = c6 < NENT ? c6 : 0u;
                unsigned c7 = p7 & 0x1FFFFu; c7 = c7 < NENT ? c7 : 0u;
                float g0 = b2f(ebf[(long long)c0*64+lane]), g1 = b2f(ebf[(long long)c1*64+lane]);
                float g2 = b2f(ebf[(long long)c2*64+lane]), g3 = b2f(ebf[(long long)c3*64+lane]);
                float g4 = b2f(ebf[(long long)c4*64+lane]), g5 = b2f(ebf[(long long)c5*64+lane]);
                float g6 = b2f(ebf[(long long)c6*64+lane]), g7 = b2f(ebf[(long long)c7*64+lane]);
                float v0 = __uint_as_float(((p0 >> 17) & 0x7FFFu) << 16);
                float v1 = __uint_as_float(((p1 >> 17) & 0x7FFFu) << 16);
                float v2 = __uint_as_float(((p2 >> 17) & 0x7FFFu) << 16);
                float v3 = __uint_as_float(((p3 >> 17) & 0x7FFFu) << 16);
                float v4 = __uint_as_float(((p4 >> 17) & 0x7FFFu) << 16);
                float v5 = __uint_as_float(((p5 >> 17) & 0x7FFFu) << 16);
                float v6 = __uint_as_float(((p6 >> 17) & 0x7FFFu) << 16);
                float v7 = __uint_as_float(((p7 >> 17) & 0x7FFFu) << 16);
                acc += v0*g0 + v1*g1 + v2*g2 + v3*g3 + v4*g4 + v5*g5 + v6*g6 + v7*g7;
            }
            for (; kk < rem; kk++){
                unsigned p = rdl(pkv, kk);
                unsigned c = p & 0x1FFFFu; c = c < NENT ? c : 0u;
                float v = __uint_as_float(((p >> 17) & 0x7FFFu) << 16);
                acc += v * b2f(ebf[(long long)c*64 + lane]);
            }
        }
        acc = fin(acc);
        long long ix = (long long)u*64 + lane;
        float x = u_src[ix];
        dst_c[ix] = usr_epi(acc, x, P2lc, latlc, q2lc, lane);
        dst_d[ix] = usr_epi(acc, x, P2ld, latld, q2ld, lane);
    }
}

// ---------------------------------------------------------------- tier A fused iter-1 (row-cached CSR words):
// blocks [0,GE): entity; blocks [GE,GE+GU): user. Both read only eA2 + CSR; outputs disjoint.
__global__ __launch_bounds__(256) void k_it1(const unsigned* __restrict__ eA2,
                                             const float* __restrict__ ent_base,
                                             const float* __restrict__ wt_c,
                                             const float* __restrict__ wt_d,
                                             const unsigned* __restrict__ rsdeg_e,
                                             const unsigned* __restrict__ epk,
                                             float* __restrict__ oe_c,
                                             float* __restrict__ oe_d,
                                             float* __restrict__ uc_io,
                                             float* __restrict__ ud_io,
                                             const float* __restrict__ usr_base,
                                             const unsigned* __restrict__ rsdeg_u,
                                             const unsigned* __restrict__ upk,
                                             const float* __restrict__ P2c,
                                             const float* __restrict__ q2c,
                                             const float* __restrict__ latc,
                                             const float* __restrict__ P2d,
                                             const float* __restrict__ q2d,
                                             const float* __restrict__ latd){
    __shared__ float sm[(R1_+R2_)*64];
    int t = threadIdx.x;
    int lane = t & 63;
    if (blockIdx.x < GE_){
        float* wlc = sm;
        float* wld = sm + R1_*64;
        for (int idx = t; idx < R1_*64; idx += 256) wlc[idx] = wt_c[idx];
        for (int idx = t; idx < R2_*64; idx += 256) wld[idx] = wt_d[idx];
        __syncthreads();
        int ent = blockIdx.x*4 + (t >> 6);
        if (ent >= NENT) return;
        unsigned rd = rflu(rsdeg_e[ent]);
        int s = (int)(rd & 0x1FFFFFu);
        int deg = (int)(rd >> 21);
        int e_ = s + deg;
        float ac = 0.f, ad = 0.f;
        for (int kb = s; kb < e_; kb += 64){
            int gi2 = kb + lane;
            unsigned pkv = epk[gi2 < e_ ? gi2 : s];
            int rem = e_ - kb; if (rem > 64) rem = 64;
            int kk = 0;
            for (; kk + 8 <= rem; kk += 8){
                unsigned p0 = rdl(pkv, kk),   p1 = rdl(pkv, kk+1), p2 = rdl(pkv, kk+2), p3 = rdl(pkv, kk+3);
                unsigned p4 = rdl(pkv, kk+4), p5 = rdl(pkv, kk+5), p6 = rdl(pkv, kk+6), p7 = rdl(pkv, kk+7);
                unsigned t0 = p0 & 0x1FFFFu; t0 = t0 < NENT ? t0 : 0u;
                unsigned t1 = p1 & 0x1FFFFu; t1 = t1 < NENT ? t1 : 0u;
                unsigned t2 = p2 & 0x1FFFFu; t2 = t2 < NENT ? t2 : 0u;
                unsigned t3 = p3 & 0x1FFFFu; t3 = t3 < NENT ? t3 : 0u;
                unsigned t4 = p4 & 0x1FFFFu; t4 = t4 < NENT ? t4 : 0u;
                unsigned t5 = p5 & 0x1FFFFu; t5 = t5 < NENT ? t5 : 0u;
                unsigned t6 = p6 & 0x1FFFFu; t6 = t6 < NENT ? t6 : 0u;
                unsigned t7 = p7 & 0x1FFFFu; t7 = t7 < NENT ? t7 : 0u;
                unsigned v0 = eA2[(long long)t0*64 + lane];
                unsigned v1 = eA2[(long long)t1*64 + lane];
                unsigned v2 = eA2[(long long)t2*64 + lane];
                unsigned v3 = eA2[(long long)t3*64 + lane];
                unsigned v4 = eA2[(long long)t4*64 + lane];
                unsigned v5 = eA2[(long long)t5*64 + lane];
                unsigned v6 = eA2[(long long)t6*64 + lane];
                unsigned v7 = eA2[(long long)t7*64 + lane];
                ac += pk_lo(v0)*wlc[((p0>>17)&15u)*64+lane] + pk_lo(v1)*wlc[((p1>>17)&15u)*64+lane]
                    + pk_lo(v2)*wlc[((p2>>17)&15u)*64+lane] + pk_lo(v3)*wlc[((p3>>17)&15u)*64+lane]
                    + pk_lo(v4)*wlc[((p4>>17)&15u)*64+lane] + pk_lo(v5)*wlc[((p5>>17)&15u)*64+lane]
                    + pk_lo(v6)*wlc[((p6>>17)&15u)*64+lane] + pk_lo(v7)*wlc[((p7>>17)&15u)*64+lane];
                ad += pk_hi(v0)*wld[((p0>>21)&31u)*64+lane] + pk_hi(v1)*wld[((p1>>21)&31u)*64+lane]
                    + pk_hi(v2)*wld[((p2>>21)&31u)*64+lane] + pk_hi(v3)*wld[((p3>>21)&31u)*64+lane]
                    + pk_hi(v4)*wld[((p4>>21)&31u)*64+lane] + pk_hi(v5)*wld[((p5>>21)&31u)*64+lane]
                    + pk_hi(v6)*wld[((p6>>21)&31u)*64+lane] + pk_hi(v7)*wld[((p7>>21)&31u)*64+lane];
            }
            for (; kk < rem; kk++){
                unsigned p = rdl(pkv, kk);
                unsigned ti = p & 0x1FFFFu; ti = ti < NENT ? ti : 0u;
                unsigned v = eA2[(long long)ti*64 + lane];
                ac += pk_lo(v) * wlc[((p>>17)&15u)*64+lane];
                ad += pk_hi(v) * wld[((p>>21)&31u)*64+lane];
            }
        }
        float inv_deg = 1.f / fmaxf((float)deg, 1.f);
        float vc = fin(ac) * inv_deg, vd = fin(ad) * inv_deg;
        float sc = vc*vc, sd = vd*vd;
        for (int m = 1; m < 64; m <<= 1){
            sc += __shfl_xor(sc, m, 64);
            sd += __shfl_xor(sd, m, 64);
        }
        long long ix = (long long)ent*64 + lane;
        float be = ent_base[ix];
        unsigned selfv = eA2[ix];
        oe_c[ix] = be + pk_lo(selfv) + vc / fmaxf(sqrtf(fin(sc)), 1e-12f);
        oe_d[ix] = be + pk_hi(selfv) + vd / fmaxf(sqrtf(fin(sd)), 1e-12f);
    } else {
        float* P2lc = sm;
        float* latlc = sm + 256;
        float* P2ld = sm + 512;
        float* latld = sm + 768;
        float* q2lc = sm + 1024;
        float* q2ld = sm + 1032;
        P2lc[t] = fin(P2c[t]); latlc[t] = fin(latc[t]);
        P2ld[t] = fin(P2d[t]); latld[t] = fin(latd[t]);
        if (t < NF_){ q2lc[t] = fin(q2c[t]); q2ld[t] = fin(q2d[t]); }
        __syncthreads();
        int u = (blockIdx.x - GE_)*4 + (t >> 6);
        if (u >= NUSR) return;
        unsigned rd = rflu(rsdeg_u[u]);
        int s = (int)(rd & 0xFFFFFu);
        int e_ = s + (int)(rd >> 20);
        float accc = 0.f, accd = 0.f;
        for (int kb = s; kb < e_; kb += 64){
            int gi2 = kb + lane;
            unsigned pkv = upk[gi2 < e_ ? gi2 : s];
            int rem = e_ - kb; if (rem > 64) rem = 64;
            int kk = 0;
            for (; kk + 8 <= rem; kk += 8){
                unsigned p0 = rdl(pkv, kk),   p1 = rdl(pkv, kk+1), p2 = rdl(pkv, kk+2), p3 = rdl(pkv, kk+3);
                unsigned p4 = rdl(pkv, kk+4), p5 = rdl(pkv, kk+5), p6 = rdl(pkv, kk+6), p7 = rdl(pkv, kk+7);
                unsigned c0 = p0 & 0x1FFFFu; c0 = c0 < NENT ? c0 : 0u;
                unsigned c1 = p1 & 0x1FFFFu; c1 = c1 < NENT ? c1 : 0u;
                unsigned c2 = p2 & 0x1FFFFu; c2 = c2 < NENT ? c2 : 0u;
                unsigned c3 = p3 & 0x1FFFFu; c3 = c3 < NENT ? c3 : 0u;
                unsigned c4 = p4 & 0x1FFFFu; c4 = c4 < NENT ? c4 : 0u;
                unsigned c5 = p5 & 0x1FFFFu; c5 = c5 < NENT ? c5 : 0u;
                unsigned c6 = p6 & 0x1FFFFu; c6 = c6 < NENT ? c6 : 0u;
                unsigned c7 = p7 & 0x1FFFFu; c7 = c7 < NENT ? c7 : 0u;
                unsigned g0 = eA2[(long long)c0*64 + lane];
                unsigned g1 = eA2[(long long)c1*64 + lane];
                unsigned g2 = eA2[(long long)c2*64 + lane];
                unsigned g3 = eA2[(long long)c3*64 + lane];
                unsigned g4 = eA2[(long long)c4*64 + lane];
                unsigned g5 = eA2[(long long)c5*64 + lane];
                unsigned g6 = eA2[(long long)c6*64 + lane];
                unsigned g7 = eA2[(long long)c7*64 + lane];
                float v0 = __uint_as_float(((p0 >> 17) & 0x7FFFu) << 16);
                float v1 = __uint_as_float(((p1 >> 17) & 0x7FFFu) << 16);
                float v2 = __uint_as_float(((p2 >> 17) & 0x7FFFu) << 16);
                float v3 = __uint_as_float(((p3 >> 17) & 0x7FFFu) << 16);
                float v4 = __uint_as_float(((p4 >> 17) & 0x7FFFu) << 16);
                float v5 = __uint_as_float(((p5 >> 17) & 0x7FFFu) << 16);
                float v6 = __uint_as_float(((p6 >> 17) & 0x7FFFu) << 16);
                float v7 = __uint_as_float(((p7 >> 17) & 0x7FFFu) << 16);
                accc += v0*pk_lo(g0) + v1*pk_lo(g1) + v2*pk_lo(g2) + v3*pk_lo(g3)
                      + v4*pk_lo(g4) + v5*pk_lo(g5) + v6*pk_lo(g6) + v7*pk_lo(g7);
                accd += v0*pk_hi(g0) + v1*pk_hi(g1) + v2*pk_hi(g2) + v3*pk_hi(g3)
                      + v4*pk_hi(g4) + v5*pk_hi(g5) + v6*pk_hi(g6) + v7*pk_hi(g7);
            }
            for (; kk < rem; kk++){
                unsigned p = rdl(pkv, kk);
                unsigned c = p & 0x1FFFFu; c = c < NENT ? c : 0u;
                float v = __uint_as_float(((p >> 17) & 0x7FFFu) << 16);
                unsigned g = eA2[(long long)c*64 + lane];
                accc += v * pk_lo(g);
                accd += v * pk_hi(g);
            }
        }
        long long ix = (long long)u*64 + lane;
        float xc = uc_io[ix], xd = ud_io[ix];
        float be = usr_base[ix];
        float vc = usr_epi(fin(accc), xc, P2lc, latlc, q2lc, lane);
        float vd = usr_epi(fin(accd), xd, P2ld, latld, q2ld, lane);
        uc_io[ix] = be + xc + vc;
        ud_io[ix] = be + xd + vd;
    }
}

// ---------------------------------------------------------------- distance correlation (2 blocks)
__global__ void k_cor(const float* __restrict__ latn1_c,
                      const float* __restrict__ ldiv,
                      const float* __restrict__ nld0, const float* __restrict__ nld1,
                      float* out){
    __shared__ float rows[NF_*64];
    __shared__ float nr[NF_];
    __shared__ float t1s[64], t2s[64], m1s[64], m2s[64];
    __shared__ float pr[256], pr2[256], pr3[256];
    __shared__ float gms[2];
    __shared__ float corsh;
    int t = threadIdx.x, b = blockIdx.x;

    if (b == 0){
        rows[t] = fin(latn1_c[t]);
        __syncthreads();
        if (t < NF_){
            float s = 0.f;
            for (int c = 0; c < 64; c++){ float v = rows[t*64+c]; s += v*v; }
            nr[t] = fmaxf(sqrtf(s), 1e-12f);
        }
        __syncthreads();
        float v = rows[t];
        __syncthreads();
        rows[t] = v + v / nr[t >> 6];               // l_res = normalize(l)+l
    } else {
        rows[t] = ldiv[t] + fin(nld0[t]) + fin(nld1[t]);  // l_d
    }
    if (t == 0) corsh = 0.f;
    __syncthreads();

    for (int i = 0; i < NF_; i++) for (int j = i+1; j < NF_; j++){
        if (t < 64){ t1s[t] = rows[i*64+t]; t2s[t] = rows[j*64+t]; }
        __syncthreads();
        int i_ = t >> 2, q = t & 3;
        float pa = 0.f, pb = 0.f;
        for (int jj = q*16; jj < q*16+16; jj++){
            float d1 = t1s[i_] - t1s[jj]; pa += sqrtf(fmaxf(d1*d1, 0.f) + 1e-8f);
            float d2 = t2s[i_] - t2s[jj]; pb += sqrtf(fmaxf(d2*d2, 0.f) + 1e-8f);
        }
        pr[t] = pa; pr2[t] = pb;
        __syncthreads();
        if (q == 0){
            m1s[i_] = (pr[t] + pr[t+1] + pr[t+2] + pr[t+3]) / 64.f;
            m2s[i_] = (pr2[t] + pr2[t+1] + pr2[t+2] + pr2[t+3]) / 64.f;
        }
        __syncthreads();
        if (t == 0){
            float s1 = 0.f, s2 = 0.f;
            for (int ii = 0; ii < 64; ii++){ s1 += m1s[ii]; s2 += m2s[ii]; }
            gms[0] = s1 / 64.f; gms[1] = s2 / 64.f;
        }
        __syncthreads();
        float gm1 = gms[0], gm2 = gms[1];
        float sab = 0.f, saa = 0.f, sbb = 0.f;
        for (int kk = 0; kk < 16; kk++){
            int idx = t*16 + kk; int ii = idx >> 6, jj = idx & 63;
            float d1 = t1s[ii] - t1s[jj];
            float A = sqrtf(fmaxf(d1*d1, 0.f) + 1e-8f) - m1s[ii] - m1s[jj] + gm1;
            float d2 = t2s[ii] - t2s[jj];
            float B = sqrtf(fmaxf(d2*d2, 0.f) + 1e-8f) - m2s[ii] - m2s[jj] + gm2;
            sab += A*B; saa += A*A; sbb += B*B;
        }
        pr[t] = sab; pr2[t] = saa; pr3[t] = sbb;
        __syncthreads();
        for (int off = 128; off; off >>= 1){
            if (t < off){ pr[t] += pr[t+off]; pr2[t] += pr2[t+off]; pr3[t] += pr3[t+off]; }
            __syncthreads();
        }
        if (t == 0){
            float dab = sqrtf(fmaxf(pr[0]/4096.f, 0.f) + 1e-8f);
            float daa = sqrtf(fmaxf(pr2[0]/4096.f, 0.f) + 1e-8f);
            float dbb = sqrtf(fmaxf(pr3[0]/4096.f, 0.f) + 1e-8f);
            corsh += dab / sqrtf(daa*dbb + 1e-8f);
        }
        __syncthreads();
    }
    if (t == 0){
        long long pos = (b == 0) ? 9600000LL : 19200001LL;
        out[pos] = corsh;
    }
}

// ================================================================ host
extern "C" void kernel_launch(void* const* d_in, const int* in_sizes, int n_in,
                              void* d_out, int out_size, void* d_ws, size_t ws_size,
                              hipStream_t stream){
    const float* user_emb   = (const float*)d_in[0];
    const float* entity_emb = (const float*)d_in[1];
    const float* latent_emb = (const float*)d_in[2];
    const float* latent_div = (const float*)d_in[3];
    const float* weight     = (const float*)d_in[4];
    const float* weight_d   = (const float*)d_in[5];
    const float* cW1 = (const float*)d_in[6];  const float* cb1 = (const float*)d_in[7];
    const float* cW2 = (const float*)d_in[8];  const float* cb2 = (const float*)d_in[9];
    const float* cWua= (const float*)d_in[10]; const float* cbua= (const float*)d_in[11];
    const float* cWwa= (const float*)d_in[12]; const float* cbwa= (const float*)d_in[13];
    const float* eW1 = (const float*)d_in[14]; const float* eb1 = (const float*)d_in[15];
    const float* eW2 = (const float*)d_in[16]; const float* eb2 = (const float*)d_in[17];
    const float* eWua= (const float*)d_in[18]; const float* ebua= (const float*)d_in[19];
    const float* eWwa= (const float*)d_in[20]; const float* ebwa= (const float*)d_in[21];
    const float* ivals = (const float*)d_in[22];
    const int* edge_index = (const int*)d_in[23];
    const int* etype      = (const int*)d_in[24];
    const int* cate       = (const int*)d_in[25];
    const int* irows      = (const int*)d_in[26];
    const int* icols      = (const int*)d_in[27];
    float* out = (float*)d_out;

    const int* head = edge_index;
    const int* tail = edge_index + EE;

    // ---- workspace carve
    char* base = (char*)d_ws;
    size_t off = 0;
    auto carve = [&](size_t bytes) -> void* {
        void* p = base + off;
        off += (bytes + 255) & ~(size_t)255;
        return p;
    };
    unsigned* rsdeg_e = (unsigned*)carve((size_t)NENT*4);
    unsigned* rsdeg_u = (unsigned*)carve((size_t)NUSR*4);
    unsigned* epk     = (unsigned*)carve((size_t)EE*4);
    unsigned* upk     = (unsigned*)carve((size_t)NNZI*4);
    float* latn[2][2]; float* nlat[2][2]; float* P2b[2][2]; float* q2b[2][2];
    for (int b = 0; b < 2; b++) for (int i = 0; i < 2; i++){
        latn[b][i] = (float*)carve(NF_*64*4);
        nlat[b][i] = (float*)carve(NF_*64*4);
        P2b [b][i] = (float*)carve(NF_*64*4);
        q2b [b][i] = (float*)carve(64);
    }
    size_t common = off;
    size_t ebuf  = (size_t)NENT*CC*2;                 // 12.8 MB bf16 entity table
    size_t ebuf2 = (size_t)NENT*CC*4;                 // 25.6 MB packed (c,d) uint table
    bool tierA = (ws_size >= common + ((ebuf + 255) & ~(size_t)255) + ((ebuf2 + 255) & ~(size_t)255));

    bf16 *ebf = nullptr; unsigned* eA2 = nullptr; bf16* eA = nullptr;
    char* scratch_base;
    if (tierA){
        ebf = (bf16*)carve(ebuf);
        eA2 = (unsigned*)carve(ebuf2);
        scratch_base = (char*)eA2;     // dead until k_it0 writes it
    } else {
        eA  = (bf16*)carve(ebuf);
        scratch_base = (char*)eA;      // dead until k_ent0 writes it
    }

    // build-time scratch aliased inside the (not-yet-written) agg buffer:
    //   deg8_e 3.2MB | deg8_u 1.6MB | ctrs | rank_e (u16, 3MB) | rank_u (u16, 2MB)
    //   ends ~10.4MB: fits tierA's 25.6MB eA2 and tierB's 12.8MB eA.
    int* deg8_e = (int*)scratch_base;                              // 8*NENT*4 = 3.2MB
    int* deg8_u = (int*)(scratch_base + 3276800);                  // 8*NUSR*4 = 1.6MB
    int* ctrs   = (int*)(scratch_base + 4915200);                  // 8B
    u16* rank_e = (u16*)(scratch_base + 5242880);                  // EE*2 = 3MB
    u16* rank_u = (u16*)(scratch_base + 8388608);                  // NNZI*2 = 2MB -> ends 10.39MB

    // out regions
    float* oe_c = out;
    float* ou_c = out + 6400000LL;
    float* oe_d = out + 9600001LL;
    float* ou_d = out + 16000001LL;

    // ---- CSR build (sharded histogram; counters zeroed by one async memset; conv fused into hist)
    hipMemsetAsync(scratch_base, 0, 4915208, stream);   // deg8_e + deg8_u + ctrs (contiguous)
    int convN = tierA ? (NENT*CC/4) : 0;
    int gh = (EE + NNZI + convN + 255)/256;
    k_hist<<<gh, 256, 0, stream>>>(head, irows, deg8_e, deg8_u, rank_e, rank_u,
                                   entity_emb, tierA ? ebf : nullptr);
    k_base2<<<(NENT+255)/256, 256, 0, stream>>>(deg8_e, deg8_u, rsdeg_e, rsdeg_u, ctrs);
    int gs = (EE + NNZI + 255)/256;
    k_scatter<<<gs, 256, 0, stream>>>(head, tail, etype, cate, irows, icols, ivals,
                                      rank_e, rank_u, deg8_e, deg8_u,
                                      rsdeg_e, rsdeg_u, epk, upk);

    // ---- latent path
    LatArgs a_c0 = {latent_emb, cW1, cb1, cW2, cb2, cWua, cbua, cWwa, cbwa, weight,
                    latn[0][0], nlat[0][0], P2b[0][0], q2b[0][0], R1_};
    LatArgs a_d0 = {latent_div, eW1, eb1, eW2, eb2, eWua, ebua, eWwa, ebwa, weight_d,
                    latn[1][0], nlat[1][0], P2b[1][0], q2b[1][0], R2_};
    k_lat2<<<2, 256, 0, stream>>>(a_c0, a_d0);
    LatArgs a_c1 = {latn[0][0], cW1+4096, cb1+64, cW2+4096, cb2+64, cWua+16, cbua+4,
                    cWwa+R1_*R1_, cbwa+R1_, weight,
                    latn[0][1], nlat[0][1], P2b[0][1], q2b[0][1], R1_};
    LatArgs a_d1 = {nlat[1][0], eW1+4096, eb1+64, eW2+4096, eb2+64, eWua+16, ebua+4,
                    eWwa+R2_*R2_, ebwa+R2_, weight_d,
                    latn[1][1], nlat[1][1], P2b[1][1], q2b[1][1], R2_};
    k_lat2<<<2, 256, 0, stream>>>(a_c1, a_d1);

    int ge = GE_, gu = GU_;
    if (tierA){
        // fused iter-0 (entity + user roles in one dispatch; both read only ebf + CSR)
        k_it0<<<ge + gu, 256, 0, stream>>>(ebf, weight, weight_d, rsdeg_e, epk, eA2,
            user_emb, rsdeg_u, upk,
            P2b[0][0], q2b[0][0], latn[0][0],
            P2b[1][0], q2b[1][0], latn[1][0], ou_c, ou_d);
        // fused iter-1 (entity + user roles; both read only eA2 + CSR; outputs disjoint)
        k_it1<<<ge + gu, 256, 0, stream>>>(eA2, entity_emb, weight, weight_d,
            rsdeg_e, epk, oe_c, oe_d,
            ou_c, ou_d, user_emb, rsdeg_u, upk,
            P2b[0][1], q2b[0][1], latn[0][1],
            P2b[1][1], q2b[1][1], latn[1][1]);
    } else {
        const float* wts[2] = {weight, weight_d};
        const int    Rs[2]  = {R1_, R2_};
        float* oes[2] = {oe_c, oe_d};
        float* ous[2] = {ou_c, ou_d};
        for (int br = 0; br < 2; br++){
            k_ent0<<<ge, 256, 0, stream>>>(entity_emb, wts[br], Rs[br], br, rsdeg_e, epk, eA);
            k_usr0<<<gu, 256, 0, stream>>>(user_emb, entity_emb, rsdeg_u, upk,
                P2b[br][0], q2b[br][0], latn[br][0], ous[br]);
            k_ent1f<<<ge, 256, 0, stream>>>(eA, entity_emb, wts[br], Rs[br], br, rsdeg_e, epk, oes[br]);
            k_usr1f<<<gu, 256, 0, stream>>>(ous[br], eA, user_emb, rsdeg_u, upk,
                P2b[br][1], q2b[br][1], latn[br][1]);
        }
    }

    // ---- distance correlations
    k_cor<<<2, 256, 0, stream>>>(latn[0][1], latent_div, nlat[1][0], nlat[1][1], out);
}

// Round 8
// 799.577 us; speedup vs baseline: 1.0384x; 1.0384x over previous
//
#include <hip/hip_runtime.h>
#include <hip/hip_bf16.h>
#include <math.h>

typedef __hip_bfloat16 bf16;
typedef unsigned short u16;

#define NUSR 50000
#define NENT 100000
#define CC   64
#define EE   1500000
#define NNZI 1000000
#define NF_  4
#define R1_  15
#define R2_  47
#define NSH  8          // counter shards (XCD-count heuristic)

__device__ __forceinline__ float b2f(bf16 x){ return __bfloat162float(x); }
__device__ __forceinline__ bf16  f2b(float x){ return __float2bfloat16(x); }
__device__ __forceinline__ float fin(float x){ return (x==x && fabsf(x) < 1e30f) ? x : 0.f; }

// RNE float->bf16 bits (matches __float2bfloat16 for finite inputs)
__device__ __forceinline__ unsigned bf16bits(float x){
    unsigned b = __float_as_uint(x);
    return (b + 0x7FFFu + ((b >> 16) & 1u)) >> 16;
}
__device__ __forceinline__ float pk_lo(unsigned p){ return __uint_as_float(p << 16); }
__device__ __forceinline__ float pk_hi(unsigned p){ return __uint_as_float(p & 0xFFFF0000u); }

// wave-uniform hoist to SGPR (full-wave call sites only)
__device__ __forceinline__ unsigned rflu(unsigned x){ return (unsigned)__builtin_amdgcn_readfirstlane((int)x); }

__device__ __forceinline__ float ldv(const float* p, long long i){ return p[i]; }
__device__ __forceinline__ float ldv(const bf16*  p, long long i){ return b2f(p[i]); }

struct LatArgs {
    const float *lin, *W1, *b1, *W2, *b2, *Wua, *bua, *Wwa, *bwa, *wt;
    float *lat, *nlat, *P2, *q2;
    int R;
};

// ---------------------------------------------------------------- histogram + per-element rank + (fused) fp32->bf16 conv
// Counters sharded 8-way by blockIdx&7 (round-robin XCD heuristic).
// Third block-role converts the entity table to bf16 (independent of hist).
__global__ void k_hist(const int* __restrict__ head, const int* __restrict__ irows,
                       int* deg8_e, int* deg8_u,
                       u16* __restrict__ rank_e, u16* __restrict__ rank_u,
                       const float* __restrict__ esrc, bf16* __restrict__ ebf){
    int i = blockIdx.x*256 + threadIdx.x;
    int shard = blockIdx.x & (NSH-1);
    if (i < EE){
        int h = head[i];
        int r = ((unsigned)h < NENT) ? atomicAdd(&deg8_e[shard*NENT + h], 1) : 0;
        rank_e[i] = (u16)((r & 8191) | (shard << 13));
    } else if (i < EE + NNZI){
        int j = i - EE;
        int rr = irows[j];
        int r = ((unsigned)rr < NUSR) ? atomicAdd(&deg8_u[shard*NUSR + rr], 1) : 0;
        rank_u[j] = (u16)((r & 8191) | (shard << 13));
    } else if (ebf){
        long long j = (long long)(i - (EE + NNZI)) * 4;
        if (j < (long long)NENT*CC){
            const float4 v = *(const float4*)(esrc + j);
            u16* o = (u16*)ebf + j;
            o[0] = (u16)bf16bits(v.x); o[1] = (u16)bf16bits(v.y);
            o[2] = (u16)bf16bits(v.z); o[3] = (u16)bf16bits(v.w);
        }
    }
}

// ---------------------------------------------------------------- row bases via wave-scan
// Also converts the per-shard counts into in-place exclusive prefixes (xoff).
__global__ void k_base2(int* deg8_e, int* deg8_u,
                        unsigned* rsdeg_e, unsigned* rsdeg_u, int* ctrs){
    int i = blockIdx.x*256 + threadIdx.x;
    int lane = threadIdx.x & 63;
    { // entities
        int d = 0;
        if (i < NENT){
            int tot = 0;
            #pragma unroll
            for (int c = 0; c < NSH; c++){
                int v = deg8_e[c*NENT + i];
                deg8_e[c*NENT + i] = tot;          // exclusive prefix (xoff)
                tot += v;
            }
            d = tot;
        }
        int incl = d;
        for (int off = 1; off < 64; off <<= 1){
            int v = __shfl_up(incl, off, 64);
            if (lane >= off) incl += v;
        }
        int tot = __shfl(incl, 63, 64);
        int base = 0;
        if (lane == 63) base = atomicAdd(&ctrs[0], tot);
        base = __shfl(base, 63, 64);
        if (i < NENT){
            unsigned rs = (unsigned)(base + incl - d);
            int dc = d < 2047 ? d : 2047;
            rsdeg_e[i] = (rs & 0x1FFFFFu) | ((unsigned)dc << 21);
        }
    }
    { // users
        int d = 0;
        if (i < NUSR){
            int tot = 0;
            #pragma unroll
            for (int c = 0; c < NSH; c++){
                int v = deg8_u[c*NUSR + i];
                deg8_u[c*NUSR + i] = tot;
                tot += v;
            }
            d = tot;
        }
        int incl = d;
        for (int off = 1; off < 64; off <<= 1){
            int v = __shfl_up(incl, off, 64);
            if (lane >= off) incl += v;
        }
        int tot = __shfl(incl, 63, 64);
        int base = 0;
        if (lane == 63) base = atomicAdd(&ctrs[1], tot);
        base = __shfl(base, 63, 64);
        if (i < NUSR){
            unsigned rs = (unsigned)(base + incl - d);
            int dc = d < 4095 ? d : 4095;
            rsdeg_u[i] = (rs & 0xFFFFFu) | ((unsigned)dc << 20);
        }
    }
}

// ---------------------------------------------------------------- CSR scatter (plain stores; no atomics)
__global__ void k_scatter(const int* __restrict__ head, const int* __restrict__ tail,
                          const int* __restrict__ etype, const int* __restrict__ cate,
                          const int* __restrict__ irows, const int* __restrict__ icols,
                          const float* __restrict__ ivals,
                          const u16* __restrict__ rank_e, const u16* __restrict__ rank_u,
                          const int* __restrict__ xoff_e, const int* __restrict__ xoff_u,
                          const unsigned* __restrict__ rsdeg_e, const unsigned* __restrict__ rsdeg_u,
                          unsigned* __restrict__ epk, unsigned* __restrict__ upk){
    int i = blockIdx.x*256 + threadIdx.x;
    if (i < EE){
        int h = head[i]; if ((unsigned)h >= NENT) return;
        unsigned tu = (unsigned)tail[i]; if (tu >= NENT) tu = 0;
        unsigned rk = rank_e[i];
        int shard = rk >> 13, r = rk & 8191;
        int slot = (int)(rsdeg_e[h] & 0x1FFFFFu) + xoff_e[shard*NENT + h] + r;
        unsigned ty = (unsigned)(etype[i] - 1) & 15u;
        unsigned cd = (unsigned)(cate[tu]  - 1) & 31u;
        if ((unsigned)slot < EE)
            epk[slot] = tu | (ty << 17) | (cd << 21);
    } else {
        int j = i - EE;
        if (j < NNZI){
            int rr = irows[j]; if ((unsigned)rr >= NUSR) return;
            unsigned c = (unsigned)icols[j]; if (c >= NENT) c = 0;
            unsigned rk = rank_u[j];
            int shard = rk >> 13, r = rk & 8191;
            int slot = (int)(rsdeg_u[rr] & 0xFFFFFu) + xoff_u[shard*NUSR + rr] + r;
            unsigned bits = __float_as_uint(ivals[j]);
            unsigned rb = bits + 0x7FFFu + ((bits >> 16) & 1u);   // RNE to bf16
            unsigned vb = (rb >> 16) & 0x7FFFu;                    // sign always 0
            if ((unsigned)slot < NNZI)
                upk[slot] = c | (vb << 17);
        }
    }
}

// ---------------------------------------------------------------- latent path: both branches, LDS-staged
__global__ void k_lat2(LatArgs A0, LatArgs A1){
    LatArgs a = (blockIdx.x == 0) ? A0 : A1;
    const int R = a.R;
    __shared__ float sW1[64*64], sW2[64*64];
    __shared__ float swt[R2_*64], wp[R2_*64];
    __shared__ float lf[NF_*64], lp1[NF_*64], lp2[NF_*64];
    __shared__ float Praw[64*NF_], qv[NF_];
    __shared__ float srp[NF_*R2_], zz[NF_*R2_];
    __shared__ float latls[NF_*64], norms[NF_];
    int t = threadIdx.x;

    for (int idx = t; idx < 64*64; idx += 256){ sW1[idx] = a.W1[idx]; sW2[idx] = a.W2[idx]; }
    for (int idx = t; idx < R*64; idx += 256) swt[idx] = a.wt[idx];
    lf[t] = fin(a.lin[t]);
    __syncthreads();

    { // l' = l@W1+b1 ; l2' = l@W2+b2
        int f = t >> 6, k = t & 63;
        float s1 = a.b1[k], s2 = a.b2[k];
        for (int c = 0; c < 64; c++){
            float lv = lf[f*64+c];
            s1 += lv * sW1[c*64+k];
            s2 += lv * sW2[c*64+k];
        }
        lp1[t] = s1; lp2[t] = s2;
    }
    __syncthreads();

    { // Praw[c][f] = sum_k W1[c,k] * l'[f,k]
        int c = t >> 2, f = t & 3;
        float s = 0.f;
        for (int k = 0; k < 64; k++) s += sW1[c*64+k] * lp1[f*64+k];
        Praw[c*4+f] = s;
    }
    if (t < NF_){
        float s = 0.f;
        for (int k = 0; k < 64; k++) s += a.b1[k] * lp1[t*64+k];
        qv[t] = s;
    }
    __syncthreads();

    { // P2[g*64+c] = sum_f Praw[c][f]*Wua[f][g]
        int g = t >> 6, c = t & 63;
        float s = 0.f;
        for (int f = 0; f < NF_; f++) s += Praw[c*4+f] * a.Wua[f*4+g];
        a.P2[g*64+c] = s;
    }
    if (t < NF_){
        float s = a.bua[t];
        for (int f = 0; f < NF_; f++) s += qv[f] * a.Wua[f*4+t];
        a.q2[t] = s;
    }
    // w' = weight@W2 + b2
    for (int idx = t; idx < R*64; idx += 256){
        int r = idx >> 6, k = idx & 63;
        float s = a.b2[k];
        for (int c = 0; c < 64; c++) s += swt[r*64+c] * sW2[c*64+k];
        wp[idx] = s;
    }
    __syncthreads();

    if (t < NF_*R){ // srp[f][r] = dot(l2'[f], w'[r])
        int f = t / R, r = t % R;
        float s = 0.f;
        for (int k = 0; k < 64; k++) s += lp2[f*64+k] * wp[r*64+k];
        srp[f*R2_ + r] = s;
    }
    __syncthreads();

    if (t < NF_*R){ // zz = leaky(srp @ Wwa + bwa)
        int f = t / R, ss = t % R;
        float v = a.bwa[ss];
        for (int r = 0; r < R; r++) v += srp[f*R2_ + r] * a.Wwa[r*R + ss];
        zz[f*R2_ + ss] = (v > 0.f) ? v : 0.2f*v;
    }
    __syncthreads();

    if (t < NF_){ // row softmax over R
        float m = -1e30f;
        for (int r = 0; r < R; r++) m = fmaxf(m, zz[t*R2_ + r]);
        float sum = 0.f;
        for (int r = 0; r < R; r++){ float e = expf(zz[t*R2_ + r] - m); zz[t*R2_ + r] = e; sum += e; }
        float inv = 1.f / sum;
        for (int r = 0; r < R; r++) zz[t*R2_ + r] *= inv;
    }
    __syncthreads();

    { // lat_new[f][c] = soft[f] @ weight
        int f = t >> 6, c = t & 63;
        float s = 0.f;
        for (int r = 0; r < R; r++) s += zz[f*R2_ + r] * swt[r*64 + c];
        latls[t] = s; a.lat[t] = s;
    }
    __syncthreads();
    if (t < NF_){
        float s = 0.f;
        for (int c = 0; c < 64; c++){ float v = latls[t*64+c]; s += v*v; }
        norms[t] = fmaxf(sqrtf(s), 1e-12f);
    }
    __syncthreads();
    a.nlat[t] = latls[t] / norms[t >> 6];
}

// ---------------------------------------------------------------- entity agg core (tier B)
template<typename SRC>
__device__ __forceinline__ float ent_row(const SRC* __restrict__ e_src, const float* wl,
                                         const unsigned* __restrict__ epk,
                                         unsigned rd, int use_d, int lane){
    rd = rflu(rd);
    int s = (int)(rd & 0x1FFFFFu);
    int deg = (int)(rd >> 21);
    int e_ = s + deg;
    float acc = 0.f;
    int k = s;
    for (; k + 4 <= e_; k += 4){
        unsigned p0 = rflu(epk[k]), p1 = rflu(epk[k+1]), p2 = rflu(epk[k+2]), p3 = rflu(epk[k+3]);
        unsigned t0 = p0 & 0x1FFFFu; t0 = t0 < NENT ? t0 : 0u;
        unsigned t1 = p1 & 0x1FFFFu; t1 = t1 < NENT ? t1 : 0u;
        unsigned t2 = p2 & 0x1FFFFu; t2 = t2 < NENT ? t2 : 0u;
        unsigned t3 = p3 & 0x1FFFFu; t3 = t3 < NENT ? t3 : 0u;
        float g0 = ldv(e_src, (long long)t0*64 + lane);
        float g1 = ldv(e_src, (long long)t1*64 + lane);
        float g2 = ldv(e_src, (long long)t2*64 + lane);
        float g3 = ldv(e_src, (long long)t3*64 + lane);
        int w0 = use_d ? (int)((p0 >> 21) & 31u) : (int)((p0 >> 17) & 15u);
        int w1 = use_d ? (int)((p1 >> 21) & 31u) : (int)((p1 >> 17) & 15u);
        int w2 = use_d ? (int)((p2 >> 21) & 31u) : (int)((p2 >> 17) & 15u);
        int w3 = use_d ? (int)((p3 >> 21) & 31u) : (int)((p3 >> 17) & 15u);
        acc += g0*wl[w0*64+lane] + g1*wl[w1*64+lane] + g2*wl[w2*64+lane] + g3*wl[w3*64+lane];
    }
    for (; k < e_; k++){
        unsigned p = rflu(epk[k]);
        unsigned ti = p & 0x1FFFFu; ti = ti < NENT ? ti : 0u;
        int wi = use_d ? (int)((p >> 21) & 31u) : (int)((p >> 17) & 15u);
        acc += ldv(e_src, (long long)ti*64 + lane) * wl[wi*64+lane];
    }
    float ea = fin(acc) / fmaxf((float)deg, 1.f);
    float sq = ea*ea;
    for (int m = 1; m < 64; m <<= 1) sq += __shfl_xor(sq, m, 64);
    float nrm = fmaxf(sqrtf(fin(sq)), 1e-12f);
    return ea / nrm;
}

// tier B iter-0: fp32 src -> bf16 ws
__global__ __launch_bounds__(256) void k_ent0(const float* __restrict__ e_src,
                                              const float* __restrict__ wtab, int R, int use_d,
                                              const unsigned* __restrict__ rsdeg_e,
                                              const unsigned* __restrict__ epk,
                                              bf16* dst){
    __shared__ float wl[R2_*64];
    int t = threadIdx.x;
    for (int idx = t; idx < R2_*64; idx += 256)
        wl[idx] = (idx < R*64) ? wtab[idx] : 0.f;
    __syncthreads();
    int ent = blockIdx.x*4 + (t >> 6);
    int lane = t & 63;
    if (ent >= NENT) return;
    float v = ent_row(e_src, wl, epk, rsdeg_e[ent], use_d, lane);
    dst[(long long)ent*64 + lane] = f2b(v);
}

// tier B iter-1 fused residual
__global__ __launch_bounds__(256) void k_ent1f(const bf16* __restrict__ e_src,
                                               const float* __restrict__ base_emb,
                                               const float* __restrict__ wtab, int R, int use_d,
                                               const unsigned* __restrict__ rsdeg_e,
                                               const unsigned* __restrict__ epk,
                                               float* dst){
    __shared__ float wl[R2_*64];
    int t = threadIdx.x;
    for (int idx = t; idx < R2_*64; idx += 256)
        wl[idx] = (idx < R*64) ? wtab[idx] : 0.f;
    __syncthreads();
    int ent = blockIdx.x*4 + (t >> 6);
    int lane = t & 63;
    if (ent >= NENT) return;
    float v = ent_row(e_src, wl, epk, rsdeg_e[ent], use_d, lane);
    long long ix = (long long)ent*64 + lane;
    dst[ix] = base_emb[ix] + b2f(e_src[ix]) + v;
}

// ---------------------------------------------------------------- user agg pieces (8-deep rflu)
template<typename ESRC>
__device__ __forceinline__ float usr_gather(const ESRC* __restrict__ e_src,
                                            const unsigned* __restrict__ upk,
                                            unsigned rd, int lane){
    rd = rflu(rd);
    int s = (int)(rd & 0xFFFFFu);
    int e_ = s + (int)(rd >> 20);
    float acc = 0.f;
    int k = s;
    for (; k + 8 <= e_; k += 8){
        unsigned p0 = rflu(upk[k]),   p1 = rflu(upk[k+1]), p2 = rflu(upk[k+2]), p3 = rflu(upk[k+3]);
        unsigned p4 = rflu(upk[k+4]), p5 = rflu(upk[k+5]), p6 = rflu(upk[k+6]), p7 = rflu(upk[k+7]);
        unsigned c0 = p0 & 0x1FFFFu; c0 = c0 < NENT ? c0 : 0u;
        unsigned c1 = p1 & 0x1FFFFu; c1 = c1 < NENT ? c1 : 0u;
        unsigned c2 = p2 & 0x1FFFFu; c2 = c2 < NENT ? c2 : 0u;
        unsigned c3 = p3 & 0x1FFFFu; c3 = c3 < NENT ? c3 : 0u;
        unsigned c4 = p4 & 0x1FFFFu; c4 = c4 < NENT ? c4 : 0u;
        unsigned c5 = p5 & 0x1FFFFu; c5 = c5 < NENT ? c5 : 0u;
        unsigned c6 = p6 & 0x1FFFFu; c6 = c6 < NENT ? c6 : 0u;
        unsigned c7 = p7 & 0x1FFFFu; c7 = c7 < NENT ? c7 : 0u;
        float g0 = ldv(e_src,(long long)c0*64+lane), g1 = ldv(e_src,(long long)c1*64+lane);
        float g2 = ldv(e_src,(long long)c2*64+lane), g3 = ldv(e_src,(long long)c3*64+lane);
        float g4 = ldv(e_src,(long long)c4*64+lane), g5 = ldv(e_src,(long long)c5*64+lane);
        float g6 = ldv(e_src,(long long)c6*64+lane), g7 = ldv(e_src,(long long)c7*64+lane);
        float v0 = __uint_as_float(((p0 >> 17) & 0x7FFFu) << 16);
        float v1 = __uint_as_float(((p1 >> 17) & 0x7FFFu) << 16);
        float v2 = __uint_as_float(((p2 >> 17) & 0x7FFFu) << 16);
        float v3 = __uint_as_float(((p3 >> 17) & 0x7FFFu) << 16);
        float v4 = __uint_as_float(((p4 >> 17) & 0x7FFFu) << 16);
        float v5 = __uint_as_float(((p5 >> 17) & 0x7FFFu) << 16);
        float v6 = __uint_as_float(((p6 >> 17) & 0x7FFFu) << 16);
        float v7 = __uint_as_float(((p7 >> 17) & 0x7FFFu) << 16);
        acc += v0*g0 + v1*g1 + v2*g2 + v3*g3 + v4*g4 + v5*g5 + v6*g6 + v7*g7;
    }
    for (; k + 4 <= e_; k += 4){
        unsigned p0 = rflu(upk[k]), p1 = rflu(upk[k+1]), p2 = rflu(upk[k+2]), p3 = rflu(upk[k+3]);
        unsigned c0 = p0 & 0x1FFFFu; c0 = c0 < NENT ? c0 : 0u;
        unsigned c1 = p1 & 0x1FFFFu; c1 = c1 < NENT ? c1 : 0u;
        unsigned c2 = p2 & 0x1FFFFu; c2 = c2 < NENT ? c2 : 0u;
        unsigned c3 = p3 & 0x1FFFFu; c3 = c3 < NENT ? c3 : 0u;
        float v0 = __uint_as_float(((p0 >> 17) & 0x7FFFu) << 16);
        float v1 = __uint_as_float(((p1 >> 17) & 0x7FFFu) << 16);
        float v2 = __uint_as_float(((p2 >> 17) & 0x7FFFu) << 16);
        float v3 = __uint_as_float(((p3 >> 17) & 0x7FFFu) << 16);
        acc += v0*ldv(e_src,(long long)c0*64+lane) + v1*ldv(e_src,(long long)c1*64+lane)
             + v2*ldv(e_src,(long long)c2*64+lane) + v3*ldv(e_src,(long long)c3*64+lane);
    }
    for (; k < e_; k++){
        unsigned p = rflu(upk[k]);
        unsigned c = p & 0x1FFFFu; c = c < NENT ? c : 0u;
        float v = __uint_as_float(((p >> 17) & 0x7FFFu) << 16);
        acc += v * ldv(e_src, (long long)c*64 + lane);
    }
    return fin(acc);
}

__device__ __forceinline__ float usr_epi(float acc, float x,
                                         const float* P2l, const float* latl, const float* q2l,
                                         int lane){
    float s0 = x*P2l[lane], s1 = x*P2l[64+lane], s2 = x*P2l[128+lane], s3 = x*P2l[192+lane];
    for (int m = 1; m < 64; m <<= 1){
        s0 += __shfl_xor(s0, m, 64);
        s1 += __shfl_xor(s1, m, 64);
        s2 += __shfl_xor(s2, m, 64);
        s3 += __shfl_xor(s3, m, 64);
    }
    s0 += q2l[0]; s1 += q2l[1]; s2 += q2l[2]; s3 += q2l[3];
    s0 = (s0 > 0.f) ? s0 : 0.2f*s0;
    s1 = (s1 > 0.f) ? s1 : 0.2f*s1;
    s2 = (s2 > 0.f) ? s2 : 0.2f*s2;
    s3 = (s3 > 0.f) ? s3 : 0.2f*s3;
    float mx = fmaxf(fmaxf(s0, s1), fmaxf(s2, s3));
    float e0 = expf(s0-mx), e1 = expf(s1-mx), e2 = expf(s2-mx), e3 = expf(s3-mx);
    float inv = 1.f / (e0+e1+e2+e3);
    float mix = fin((e0*latl[lane] + e1*latl[64+lane] + e2*latl[128+lane] + e3*latl[192+lane]) * inv);
    float ua = acc * (1.f + mix);
    float sq = ua*ua;
    for (int m = 1; m < 64; m <<= 1) sq += __shfl_xor(sq, m, 64);
    float nrm = fmaxf(sqrtf(fin(sq)), 1e-12f);
    return ua / nrm;
}

// tier B iter-0 user
__global__ __launch_bounds__(256) void k_usr0(const float* __restrict__ u_src,
                                              const float* __restrict__ e_src,
                                              const unsigned* __restrict__ rsdeg_u,
                                              const unsigned* __restrict__ upk,
                                              const float* __restrict__ P2,
                                              const float* __restrict__ q2,
                                              const float* __restrict__ lat_new,
                                              float* dst){
    __shared__ float P2l[NF_*64], latl[NF_*64], q2l[NF_];
    int t = threadIdx.x;
    P2l[t] = fin(P2[t]); latl[t] = fin(lat_new[t]);
    if (t < NF_) q2l[t] = fin(q2[t]);
    __syncthreads();
    int u = blockIdx.x*4 + (t >> 6);
    int lane = t & 63;
    if (u >= NUSR) return;
    float acc = usr_gather(e_src, upk, rsdeg_u[u], lane);
    float x = u_src[(long long)u*64 + lane];
    dst[(long long)u*64 + lane] = usr_epi(acc, x, P2l, latl, q2l, lane);
}

// tier B iter-1 user
__global__ __launch_bounds__(256) void k_usr1f(float* u_io,
                                               const bf16* __restrict__ e_src,
                                               const float* __restrict__ base_emb,
                                               const unsigned* __restrict__ rsdeg_u,
                                               const unsigned* __restrict__ upk,
                                               const float* __restrict__ P2,
                                               const float* __restrict__ q2,
                                               const float* __restrict__ lat_new){
    __shared__ float P2l[NF_*64], latl[NF_*64], q2l[NF_];
    int t = threadIdx.x;
    P2l[t] = fin(P2[t]); latl[t] = fin(lat_new[t]);
    if (t < NF_) q2l[t] = fin(q2[t]);
    __syncthreads();
    int u = blockIdx.x*4 + (t >> 6);
    int lane = t & 63;
    if (u >= NUSR) return;
    float acc = usr_gather(e_src, upk, rsdeg_u[u], lane);
    long long ix = (long long)u*64 + lane;
    float x = u_io[ix];
    float v = usr_epi(acc, x, P2l, latl, q2l, lane);
    u_io[ix] = base_emb[ix] + x + v;
}

// ---------------------------------------------------------------- tier A fused iter-0 (8-deep rflu):
// blocks [0,GE): entity gather -> packed eA2; blocks [GE,GE+GU): user gather -> ou_c/ou_d.
#define GE_ ((NENT+3)/4)
#define GU_ ((NUSR+3)/4)
__global__ __launch_bounds__(256) void k_it0(const bf16* __restrict__ ebf,
                                             const float* __restrict__ wt_c,
                                             const float* __restrict__ wt_d,
                                             const unsigned* __restrict__ rsdeg_e,
                                             const unsigned* __restrict__ epk,
                                             unsigned* __restrict__ eA2,
                                             const float* __restrict__ u_src,
                                             const unsigned* __restrict__ rsdeg_u,
                                             const unsigned* __restrict__ upk,
                                             const float* __restrict__ P2c,
                                             const float* __restrict__ q2c,
                                             const float* __restrict__ latc,
                                             const float* __restrict__ P2d,
                                             const float* __restrict__ q2d,
                                             const float* __restrict__ latd,
                                             float* __restrict__ dst_c,
                                             float* __restrict__ dst_d){
    __shared__ float sm[(R1_+R2_)*64];      // 15872 B, shared by both roles
    int t = threadIdx.x;
    int lane = t & 63;
    if (blockIdx.x < GE_){
        float* wlc = sm;                    // R1_*64
        float* wld = sm + R1_*64;           // R2_*64
        for (int idx = t; idx < R1_*64; idx += 256) wlc[idx] = wt_c[idx];
        for (int idx = t; idx < R2_*64; idx += 256) wld[idx] = wt_d[idx];
        __syncthreads();
        int ent = blockIdx.x*4 + (t >> 6);
        if (ent >= NENT) return;
        unsigned rd = rflu(rsdeg_e[ent]);
        int s = (int)(rd & 0x1FFFFFu);
        int deg = (int)(rd >> 21);
        int e_ = s + deg;
        float ac = 0.f, ad = 0.f;
        int k = s;
        for (; k + 8 <= e_; k += 8){
            unsigned p0 = rflu(epk[k]),   p1 = rflu(epk[k+1]), p2 = rflu(epk[k+2]), p3 = rflu(epk[k+3]);
            unsigned p4 = rflu(epk[k+4]), p5 = rflu(epk[k+5]), p6 = rflu(epk[k+6]), p7 = rflu(epk[k+7]);
            unsigned t0 = p0 & 0x1FFFFu; t0 = t0 < NENT ? t0 : 0u;
            unsigned t1 = p1 & 0x1FFFFu; t1 = t1 < NENT ? t1 : 0u;
            unsigned t2 = p2 & 0x1FFFFu; t2 = t2 < NENT ? t2 : 0u;
            unsigned t3 = p3 & 0x1FFFFu; t3 = t3 < NENT ? t3 : 0u;
            unsigned t4 = p4 & 0x1FFFFu; t4 = t4 < NENT ? t4 : 0u;
            unsigned t5 = p5 & 0x1FFFFu; t5 = t5 < NENT ? t5 : 0u;
            unsigned t6 = p6 & 0x1FFFFu; t6 = t6 < NENT ? t6 : 0u;
            unsigned t7 = p7 & 0x1FFFFu; t7 = t7 < NENT ? t7 : 0u;
            float g0 = b2f(ebf[(long long)t0*64 + lane]);
            float g1 = b2f(ebf[(long long)t1*64 + lane]);
            float g2 = b2f(ebf[(long long)t2*64 + lane]);
            float g3 = b2f(ebf[(long long)t3*64 + lane]);
            float g4 = b2f(ebf[(long long)t4*64 + lane]);
            float g5 = b2f(ebf[(long long)t5*64 + lane]);
            float g6 = b2f(ebf[(long long)t6*64 + lane]);
            float g7 = b2f(ebf[(long long)t7*64 + lane]);
            ac += g0*wlc[((p0>>17)&15u)*64+lane] + g1*wlc[((p1>>17)&15u)*64+lane]
                + g2*wlc[((p2>>17)&15u)*64+lane] + g3*wlc[((p3>>17)&15u)*64+lane]
                + g4*wlc[((p4>>17)&15u)*64+lane] + g5*wlc[((p5>>17)&15u)*64+lane]
                + g6*wlc[((p6>>17)&15u)*64+lane] + g7*wlc[((p7>>17)&15u)*64+lane];
            ad += g0*wld[((p0>>21)&31u)*64+lane] + g1*wld[((p1>>21)&31u)*64+lane]
                + g2*wld[((p2>>21)&31u)*64+lane] + g3*wld[((p3>>21)&31u)*64+lane]
                + g4*wld[((p4>>21)&31u)*64+lane] + g5*wld[((p5>>21)&31u)*64+lane]
                + g6*wld[((p6>>21)&31u)*64+lane] + g7*wld[((p7>>21)&31u)*64+lane];
        }
        for (; k + 4 <= e_; k += 4){
            unsigned p0 = rflu(epk[k]), p1 = rflu(epk[k+1]), p2 = rflu(epk[k+2]), p3 = rflu(epk[k+3]);
            unsigned t0 = p0 & 0x1FFFFu; t0 = t0 < NENT ? t0 : 0u;
            unsigned t1 = p1 & 0x1FFFFu; t1 = t1 < NENT ? t1 : 0u;
            unsigned t2 = p2 & 0x1FFFFu; t2 = t2 < NENT ? t2 : 0u;
            unsigned t3 = p3 & 0x1FFFFu; t3 = t3 < NENT ? t3 : 0u;
            float g0 = b2f(ebf[(long long)t0*64 + lane]);
            float g1 = b2f(ebf[(long long)t1*64 + lane]);
            float g2 = b2f(ebf[(long long)t2*64 + lane]);
            float g3 = b2f(ebf[(long long)t3*64 + lane]);
            ac += g0*wlc[((p0>>17)&15u)*64+lane] + g1*wlc[((p1>>17)&15u)*64+lane]
                + g2*wlc[((p2>>17)&15u)*64+lane] + g3*wlc[((p3>>17)&15u)*64+lane];
            ad += g0*wld[((p0>>21)&31u)*64+lane] + g1*wld[((p1>>21)&31u)*64+lane]
                + g2*wld[((p2>>21)&31u)*64+lane] + g3*wld[((p3>>21)&31u)*64+lane];
        }
        for (; k < e_; k++){
            unsigned p = rflu(epk[k]);
            unsigned ti = p & 0x1FFFFu; ti = ti < NENT ? ti : 0u;
            float g = b2f(ebf[(long long)ti*64 + lane]);
            ac += g*wlc[((p>>17)&15u)*64+lane];
            ad += g*wld[((p>>21)&31u)*64+lane];
        }
        float inv_deg = 1.f / fmaxf((float)deg, 1.f);
        float ec = fin(ac) * inv_deg, ed = fin(ad) * inv_deg;
        float sc = ec*ec, sd = ed*ed;
        for (int m = 1; m < 64; m <<= 1){
            sc += __shfl_xor(sc, m, 64);
            sd += __shfl_xor(sd, m, 64);
        }
        float vc = ec / fmaxf(sqrtf(fin(sc)), 1e-12f);
        float vd = ed / fmaxf(sqrtf(fin(sd)), 1e-12f);
        eA2[(long long)ent*64 + lane] = bf16bits(vc) | (bf16bits(vd) << 16);
    } else {
        float* P2lc = sm;            // 256
        float* latlc = sm + 256;     // 256
        float* P2ld = sm + 512;      // 256
        float* latld = sm + 768;     // 256
        float* q2lc = sm + 1024;     // 4
        float* q2ld = sm + 1032;     // 4
        P2lc[t] = fin(P2c[t]); latlc[t] = fin(latc[t]);
        P2ld[t] = fin(P2d[t]); latld[t] = fin(latd[t]);
        if (t < NF_){ q2lc[t] = fin(q2c[t]); q2ld[t] = fin(q2d[t]); }
        __syncthreads();
        int u = (blockIdx.x - GE_)*4 + (t >> 6);
        if (u >= NUSR) return;
        float acc = usr_gather(ebf, upk, rsdeg_u[u], lane);
        long long ix = (long long)u*64 + lane;
        float x = u_src[ix];
        dst_c[ix] = usr_epi(acc, x, P2lc, latlc, q2lc, lane);
        dst_d[ix] = usr_epi(acc, x, P2ld, latld, q2ld, lane);
    }
}

// ---------------------------------------------------------------- tier A fused iter-1 (8-deep rflu):
// blocks [0,GE): entity; blocks [GE,GE+GU): user. Both read only eA2 + CSR; outputs disjoint.
__global__ __launch_bounds__(256) void k_it1(const unsigned* __restrict__ eA2,
                                             const float* __restrict__ ent_base,
                                             const float* __restrict__ wt_c,
                                             const float* __restrict__ wt_d,
                                             const unsigned* __restrict__ rsdeg_e,
                                             const unsigned* __restrict__ epk,
                                             float* __restrict__ oe_c,
                                             float* __restrict__ oe_d,
                                             float* __restrict__ uc_io,
                                             float* __restrict__ ud_io,
                                             const float* __restrict__ usr_base,
                                             const unsigned* __restrict__ rsdeg_u,
                                             const unsigned* __restrict__ upk,
                                             const float* __restrict__ P2c,
                                             const float* __restrict__ q2c,
                                             const float* __restrict__ latc,
                                             const float* __restrict__ P2d,
                                             const float* __restrict__ q2d,
                                             const float* __restrict__ latd){
    __shared__ float sm[(R1_+R2_)*64];
    int t = threadIdx.x;
    int lane = t & 63;
    if (blockIdx.x < GE_){
        float* wlc = sm;
        float* wld = sm + R1_*64;
        for (int idx = t; idx < R1_*64; idx += 256) wlc[idx] = wt_c[idx];
        for (int idx = t; idx < R2_*64; idx += 256) wld[idx] = wt_d[idx];
        __syncthreads();
        int ent = blockIdx.x*4 + (t >> 6);
        if (ent >= NENT) return;
        unsigned rd = rflu(rsdeg_e[ent]);
        int s = (int)(rd & 0x1FFFFFu);
        int deg = (int)(rd >> 21);
        int e_ = s + deg;
        float ac = 0.f, ad = 0.f;
        int k = s;
        for (; k + 8 <= e_; k += 8){
            unsigned p0 = rflu(epk[k]),   p1 = rflu(epk[k+1]), p2 = rflu(epk[k+2]), p3 = rflu(epk[k+3]);
            unsigned p4 = rflu(epk[k+4]), p5 = rflu(epk[k+5]), p6 = rflu(epk[k+6]), p7 = rflu(epk[k+7]);
            unsigned t0 = p0 & 0x1FFFFu; t0 = t0 < NENT ? t0 : 0u;
            unsigned t1 = p1 & 0x1FFFFu; t1 = t1 < NENT ? t1 : 0u;
            unsigned t2 = p2 & 0x1FFFFu; t2 = t2 < NENT ? t2 : 0u;
            unsigned t3 = p3 & 0x1FFFFu; t3 = t3 < NENT ? t3 : 0u;
            unsigned t4 = p4 & 0x1FFFFu; t4 = t4 < NENT ? t4 : 0u;
            unsigned t5 = p5 & 0x1FFFFu; t5 = t5 < NENT ? t5 : 0u;
            unsigned t6 = p6 & 0x1FFFFu; t6 = t6 < NENT ? t6 : 0u;
            unsigned t7 = p7 & 0x1FFFFu; t7 = t7 < NENT ? t7 : 0u;
            unsigned v0 = eA2[(long long)t0*64 + lane];
            unsigned v1 = eA2[(long long)t1*64 + lane];
            unsigned v2 = eA2[(long long)t2*64 + lane];
            unsigned v3 = eA2[(long long)t3*64 + lane];
            unsigned v4 = eA2[(long long)t4*64 + lane];
            unsigned v5 = eA2[(long long)t5*64 + lane];
            unsigned v6 = eA2[(long long)t6*64 + lane];
            unsigned v7 = eA2[(long long)t7*64 + lane];
            ac += pk_lo(v0)*wlc[((p0>>17)&15u)*64+lane] + pk_lo(v1)*wlc[((p1>>17)&15u)*64+lane]
                + pk_lo(v2)*wlc[((p2>>17)&15u)*64+lane] + pk_lo(v3)*wlc[((p3>>17)&15u)*64+lane]
                + pk_lo(v4)*wlc[((p4>>17)&15u)*64+lane] + pk_lo(v5)*wlc[((p5>>17)&15u)*64+lane]
                + pk_lo(v6)*wlc[((p6>>17)&15u)*64+lane] + pk_lo(v7)*wlc[((p7>>17)&15u)*64+lane];
            ad += pk_hi(v0)*wld[((p0>>21)&31u)*64+lane] + pk_hi(v1)*wld[((p1>>21)&31u)*64+lane]
                + pk_hi(v2)*wld[((p2>>21)&31u)*64+lane] + pk_hi(v3)*wld[((p3>>21)&31u)*64+lane]
                + pk_hi(v4)*wld[((p4>>21)&31u)*64+lane] + pk_hi(v5)*wld[((p5>>21)&31u)*64+lane]
                + pk_hi(v6)*wld[((p6>>21)&31u)*64+lane] + pk_hi(v7)*wld[((p7>>21)&31u)*64+lane];
        }
        for (; k + 4 <= e_; k += 4){
            unsigned p0 = rflu(epk[k]), p1 = rflu(epk[k+1]), p2 = rflu(epk[k+2]), p3 = rflu(epk[k+3]);
            unsigned t0 = p0 & 0x1FFFFu; t0 = t0 < NENT ? t0 : 0u;
            unsigned t1 = p1 & 0x1FFFFu; t1 = t1 < NENT ? t1 : 0u;
            unsigned t2 = p2 & 0x1FFFFu; t2 = t2 < NENT ? t2 : 0u;
            unsigned t3 = p3 & 0x1FFFFu; t3 = t3 < NENT ? t3 : 0u;
            unsigned v0 = eA2[(long long)t0*64 + lane];
            unsigned v1 = eA2[(long long)t1*64 + lane];
            unsigned v2 = eA2[(long long)t2*64 + lane];
            unsigned v3 = eA2[(long long)t3*64 + lane];
            ac += pk_lo(v0)*wlc[((p0>>17)&15u)*64+lane] + pk_lo(v1)*wlc[((p1>>17)&15u)*64+lane]
                + pk_lo(v2)*wlc[((p2>>17)&15u)*64+lane] + pk_lo(v3)*wlc[((p3>>17)&15u)*64+lane];
            ad += pk_hi(v0)*wld[((p0>>21)&31u)*64+lane] + pk_hi(v1)*wld[((p1>>21)&31u)*64+lane]
                + pk_hi(v2)*wld[((p2>>21)&31u)*64+lane] + pk_hi(v3)*wld[((p3>>21)&31u)*64+lane];
        }
        for (; k < e_; k++){
            unsigned p = rflu(epk[k]);
            unsigned ti = p & 0x1FFFFu; ti = ti < NENT ? ti : 0u;
            unsigned v = eA2[(long long)ti*64 + lane];
            ac += pk_lo(v) * wlc[((p>>17)&15u)*64+lane];
            ad += pk_hi(v) * wld[((p>>21)&31u)*64+lane];
        }
        float inv_deg = 1.f / fmaxf((float)deg, 1.f);
        float vc = fin(ac) * inv_deg, vd = fin(ad) * inv_deg;
        float sc = vc*vc, sd = vd*vd;
        for (int m = 1; m < 64; m <<= 1){
            sc += __shfl_xor(sc, m, 64);
            sd += __shfl_xor(sd, m, 64);
        }
        long long ix = (long long)ent*64 + lane;
        float be = ent_base[ix];
        unsigned selfv = eA2[ix];
        oe_c[ix] = be + pk_lo(selfv) + vc / fmaxf(sqrtf(fin(sc)), 1e-12f);
        oe_d[ix] = be + pk_hi(selfv) + vd / fmaxf(sqrtf(fin(sd)), 1e-12f);
    } else {
        float* P2lc = sm;
        float* latlc = sm + 256;
        float* P2ld = sm + 512;
        float* latld = sm + 768;
        float* q2lc = sm + 1024;
        float* q2ld = sm + 1032;
        P2lc[t] = fin(P2c[t]); latlc[t] = fin(latc[t]);
        P2ld[t] = fin(P2d[t]); latld[t] = fin(latd[t]);
        if (t < NF_){ q2lc[t] = fin(q2c[t]); q2ld[t] = fin(q2d[t]); }
        __syncthreads();
        int u = (blockIdx.x - GE_)*4 + (t >> 6);
        if (u >= NUSR) return;
        unsigned rd = rflu(rsdeg_u[u]);
        int s = (int)(rd & 0xFFFFFu);
        int e_ = s + (int)(rd >> 20);
        float accc = 0.f, accd = 0.f;
        int k = s;
        for (; k + 8 <= e_; k += 8){
            unsigned p0 = rflu(upk[k]),   p1 = rflu(upk[k+1]), p2 = rflu(upk[k+2]), p3 = rflu(upk[k+3]);
            unsigned p4 = rflu(upk[k+4]), p5 = rflu(upk[k+5]), p6 = rflu(upk[k+6]), p7 = rflu(upk[k+7]);
            unsigned c0 = p0 & 0x1FFFFu; c0 = c0 < NENT ? c0 : 0u;
            unsigned c1 = p1 & 0x1FFFFu; c1 = c1 < NENT ? c1 : 0u;
            unsigned c2 = p2 & 0x1FFFFu; c2 = c2 < NENT ? c2 : 0u;
            unsigned c3 = p3 & 0x1FFFFu; c3 = c3 < NENT ? c3 : 0u;
            unsigned c4 = p4 & 0x1FFFFu; c4 = c4 < NENT ? c4 : 0u;
            unsigned c5 = p5 & 0x1FFFFu; c5 = c5 < NENT ? c5 : 0u;
            unsigned c6 = p6 & 0x1FFFFu; c6 = c6 < NENT ? c6 : 0u;
            unsigned c7 = p7 & 0x1FFFFu; c7 = c7 < NENT ? c7 : 0u;
            unsigned g0 = eA2[(long long)c0*64 + lane];
            unsigned g1 = eA2[(long long)c1*64 + lane];
            unsigned g2 = eA2[(long long)c2*64 + lane];
            unsigned g3 = eA2[(long long)c3*64 + lane];
            unsigned g4 = eA2[(long long)c4*64 + lane];
            unsigned g5 = eA2[(long long)c5*64 + lane];
            unsigned g6 = eA2[(long long)c6*64 + lane];
            unsigned g7 = eA2[(long long)c7*64 + lane];
            float v0 = __uint_as_float(((p0 >> 17) & 0x7FFFu) << 16);
            float v1 = __uint_as_float(((p1 >> 17) & 0x7FFFu) << 16);
            float v2 = __uint_as_float(((p2 >> 17) & 0x7FFFu) << 16);
            float v3 = __uint_as_float(((p3 >> 17) & 0x7FFFu) << 16);
            float v4 = __uint_as_float(((p4 >> 17) & 0x7FFFu) << 16);
            float v5 = __uint_as_float(((p5 >> 17) & 0x7FFFu) << 16);
            float v6 = __uint_as_float(((p6 >> 17) & 0x7FFFu) << 16);
            float v7 = __uint_as_float(((p7 >> 17) & 0x7FFFu) << 16);
            accc += v0*pk_lo(g0) + v1*pk_lo(g1) + v2*pk_lo(g2) + v3*pk_lo(g3)
                  + v4*pk_lo(g4) + v5*pk_lo(g5) + v6*pk_lo(g6) + v7*pk_lo(g7);
            accd += v0*pk_hi(g0) + v1*pk_hi(g1) + v2*pk_hi(g2) + v3*pk_hi(g3)
                  + v4*pk_hi(g4) + v5*pk_hi(g5) + v6*pk_hi(g6) + v7*pk_hi(g7);
        }
        for (; k + 4 <= e_; k += 4){
            unsigned p0 = rflu(upk[k]), p1 = rflu(upk[k+1]), p2 = rflu(upk[k+2]), p3 = rflu(upk[k+3]);
            unsigned c0 = p0 & 0x1FFFFu; c0 = c0 < NENT ? c0 : 0u;
            unsigned c1 = p1 & 0x1FFFFu; c1 = c1 < NENT ? c1 : 0u;
            unsigned c2 = p2 & 0x1FFFFu; c2 = c2 < NENT ? c2 : 0u;
            unsigned c3 = p3 & 0x1FFFFu; c3 = c3 < NENT ? c3 : 0u;
            float v0 = __uint_as_float(((p0 >> 17) & 0x7FFFu) << 16);
            float v1 = __uint_as_float(((p1 >> 17) & 0x7FFFu) << 16);
            float v2 = __uint_as_float(((p2 >> 17) & 0x7FFFu) << 16);
            float v3 = __uint_as_float(((p3 >> 17) & 0x7FFFu) << 16);
            unsigned g0 = eA2[(long long)c0*64 + lane];
            unsigned g1 = eA2[(long long)c1*64 + lane];
            unsigned g2 = eA2[(long long)c2*64 + lane];
            unsigned g3 = eA2[(long long)c3*64 + lane];
            accc += v0*pk_lo(g0) + v1*pk_lo(g1) + v2*pk_lo(g2) + v3*pk_lo(g3);
            accd += v0*pk_hi(g0) + v1*pk_hi(g1) + v2*pk_hi(g2) + v3*pk_hi(g3);
        }
        for (; k < e_; k++){
            unsigned p = rflu(upk[k]);
            unsigned c = p & 0x1FFFFu; c = c < NENT ? c : 0u;
            float v = __uint_as_float(((p >> 17) & 0x7FFFu) << 16);
            unsigned g = eA2[(long long)c*64 + lane];
            accc += v * pk_lo(g);
            accd += v * pk_hi(g);
        }
        long long ix = (long long)u*64 + lane;
        float xc = uc_io[ix], xd = ud_io[ix];
        float be = usr_base[ix];
        float vc = usr_epi(fin(accc), xc, P2lc, latlc, q2lc, lane);
        float vd = usr_epi(fin(accd), xd, P2ld, latld, q2ld, lane);
        uc_io[ix] = be + xc + vc;
        ud_io[ix] = be + xd + vd;
    }
}

// ---------------------------------------------------------------- distance correlation (2 blocks)
__global__ void k_cor(const float* __restrict__ latn1_c,
                      const float* __restrict__ ldiv,
                      const float* __restrict__ nld0, const float* __restrict__ nld1,
                      float* out){
    __shared__ float rows[NF_*64];
    __shared__ float nr[NF_];
    __shared__ float t1s[64], t2s[64], m1s[64], m2s[64];
    __shared__ float pr[256], pr2[256], pr3[256];
    __shared__ float gms[2];
    __shared__ float corsh;
    int t = threadIdx.x, b = blockIdx.x;

    if (b == 0){
        rows[t] = fin(latn1_c[t]);
        __syncthreads();
        if (t < NF_){
            float s = 0.f;
            for (int c = 0; c < 64; c++){ float v = rows[t*64+c]; s += v*v; }
            nr[t] = fmaxf(sqrtf(s), 1e-12f);
        }
        __syncthreads();
        float v = rows[t];
        __syncthreads();
        rows[t] = v + v / nr[t >> 6];               // l_res = normalize(l)+l
    } else {
        rows[t] = ldiv[t] + fin(nld0[t]) + fin(nld1[t]);  // l_d
    }
    if (t == 0) corsh = 0.f;
    __syncthreads();

    for (int i = 0; i < NF_; i++) for (int j = i+1; j < NF_; j++){
        if (t < 64){ t1s[t] = rows[i*64+t]; t2s[t] = rows[j*64+t]; }
        __syncthreads();
        int i_ = t >> 2, q = t & 3;
        float pa = 0.f, pb = 0.f;
        for (int jj = q*16; jj < q*16+16; jj++){
            float d1 = t1s[i_] - t1s[jj]; pa += sqrtf(fmaxf(d1*d1, 0.f) + 1e-8f);
            float d2 = t2s[i_] - t2s[jj]; pb += sqrtf(fmaxf(d2*d2, 0.f) + 1e-8f);
        }
        pr[t] = pa; pr2[t] = pb;
        __syncthreads();
        if (q == 0){
            m1s[i_] = (pr[t] + pr[t+1] + pr[t+2] + pr[t+3]) / 64.f;
            m2s[i_] = (pr2[t] + pr2[t+1] + pr2[t+2] + pr2[t+3]) / 64.f;
        }
        __syncthreads();
        if (t == 0){
            float s1 = 0.f, s2 = 0.f;
            for (int ii = 0; ii < 64; ii++){ s1 += m1s[ii]; s2 += m2s[ii]; }
            gms[0] = s1 / 64.f; gms[1] = s2 / 64.f;
        }
        __syncthreads();
        float gm1 = gms[0], gm2 = gms[1];
        float sab = 0.f, saa = 0.f, sbb = 0.f;
        for (int kk = 0; kk < 16; kk++){
            int idx = t*16 + kk; int ii = idx >> 6, jj = idx & 63;
            float d1 = t1s[ii] - t1s[jj];
            float A = sqrtf(fmaxf(d1*d1, 0.f) + 1e-8f) - m1s[ii] - m1s[jj] + gm1;
            float d2 = t2s[ii] - t2s[jj];
            float B = sqrtf(fmaxf(d2*d2, 0.f) + 1e-8f) - m2s[ii] - m2s[jj] + gm2;
            sab += A*B; saa += A*A; sbb += B*B;
        }
        pr[t] = sab; pr2[t] = saa; pr3[t] = sbb;
        __syncthreads();
        for (int off = 128; off; off >>= 1){
            if (t < off){ pr[t] += pr[t+off]; pr2[t] += pr2[t+off]; pr3[t] += pr3[t+off]; }
            __syncthreads();
        }
        if (t == 0){
            float dab = sqrtf(fmaxf(pr[0]/4096.f, 0.f) + 1e-8f);
            float daa = sqrtf(fmaxf(pr2[0]/4096.f, 0.f) + 1e-8f);
            float dbb = sqrtf(fmaxf(pr3[0]/4096.f, 0.f) + 1e-8f);
            corsh += dab / sqrtf(daa*dbb + 1e-8f);
        }
        __syncthreads();
    }
    if (t == 0){
        long long pos = (b == 0) ? 9600000LL : 19200001LL;
        out[pos] = corsh;
    }
}

// ================================================================ host
extern "C" void kernel_launch(void* const* d_in, const int* in_sizes, int n_in,
                              void* d_out, int out_size, void* d_ws, size_t ws_size,
                              hipStream_t stream){
    const float* user_emb   = (const float*)d_in[0];
    const float* entity_emb = (const float*)d_in[1];
    const float* latent_emb = (const float*)d_in[2];
    const float* latent_div = (const float*)d_in[3];
    const float* weight     = (const float*)d_in[4];
    const float* weight_d   = (const float*)d_in[5];
    const float* cW1 = (const float*)d_in[6];  const float* cb1 = (const float*)d_in[7];
    const float* cW2 = (const float*)d_in[8];  const float* cb2 = (const float*)d_in[9];
    const float* cWua= (const float*)d_in[10]; const float* cbua= (const float*)d_in[11];
    const float* cWwa= (const float*)d_in[12]; const float* cbwa= (const float*)d_in[13];
    const float* eW1 = (const float*)d_in[14]; const float* eb1 = (const float*)d_in[15];
    const float* eW2 = (const float*)d_in[16]; const float* eb2 = (const float*)d_in[17];
    const float* eWua= (const float*)d_in[18]; const float* ebua= (const float*)d_in[19];
    const float* eWwa= (const float*)d_in[20]; const float* ebwa= (const float*)d_in[21];
    const float* ivals = (const float*)d_in[22];
    const int* edge_index = (const int*)d_in[23];
    const int* etype      = (const int*)d_in[24];
    const int* cate       = (const int*)d_in[25];
    const int* irows      = (const int*)d_in[26];
    const int* icols      = (const int*)d_in[27];
    float* out = (float*)d_out;

    const int* head = edge_index;
    const int* tail = edge_index + EE;

    // ---- workspace carve
    char* base = (char*)d_ws;
    size_t off = 0;
    auto carve = [&](size_t bytes) -> void* {
        void* p = base + off;
        off += (bytes + 255) & ~(size_t)255;
        return p;
    };
    unsigned* rsdeg_e = (unsigned*)carve((size_t)NENT*4);
    unsigned* rsdeg_u = (unsigned*)carve((size_t)NUSR*4);
    unsigned* epk     = (unsigned*)carve((size_t)EE*4);
    unsigned* upk     = (unsigned*)carve((size_t)NNZI*4);
    float* latn[2][2]; float* nlat[2][2]; float* P2b[2][2]; float* q2b[2][2];
    for (int b = 0; b < 2; b++) for (int i = 0; i < 2; i++){
        latn[b][i] = (float*)carve(NF_*64*4);
        nlat[b][i] = (float*)carve(NF_*64*4);
        P2b [b][i] = (float*)carve(NF_*64*4);
        q2b [b][i] = (float*)carve(64);
    }
    size_t common = off;
    size_t ebuf  = (size_t)NENT*CC*2;                 // 12.8 MB bf16 entity table
    size_t ebuf2 = (size_t)NENT*CC*4;                 // 25.6 MB packed (c,d) uint table
    bool tierA = (ws_size >= common + ((ebuf + 255) & ~(size_t)255) + ((ebuf2 + 255) & ~(size_t)255));

    bf16 *ebf = nullptr; unsigned* eA2 = nullptr; bf16* eA = nullptr;
    char* scratch_base;
    if (tierA){
        ebf = (bf16*)carve(ebuf);
        eA2 = (unsigned*)carve(ebuf2);
        scratch_base = (char*)eA2;     // dead until k_it0 writes it
    } else {
        eA  = (bf16*)carve(ebuf);
        scratch_base = (char*)eA;      // dead until k_ent0 writes it
    }

    // build-time scratch aliased inside the (not-yet-written) agg buffer:
    //   deg8_e 3.2MB | deg8_u 1.6MB | ctrs | rank_e (u16, 3MB) | rank_u (u16, 2MB)
    //   ends ~10.4MB: fits tierA's 25.6MB eA2 and tierB's 12.8MB eA.
    int* deg8_e = (int*)scratch_base;                              // 8*NENT*4 = 3.2MB
    int* deg8_u = (int*)(scratch_base + 3276800);                  // 8*NUSR*4 = 1.6MB
    int* ctrs   = (int*)(scratch_base + 4915200);                  // 8B
    u16* rank_e = (u16*)(scratch_base + 5242880);                  // EE*2 = 3MB
    u16* rank_u = (u16*)(scratch_base + 8388608);                  // NNZI*2 = 2MB -> ends 10.39MB

    // out regions
    float* oe_c = out;
    float* ou_c = out + 6400000LL;
    float* oe_d = out + 9600001LL;
    float* ou_d = out + 16000001LL;

    // ---- CSR build (sharded histogram; counters zeroed by one async memset; conv fused into hist)
    hipMemsetAsync(scratch_base, 0, 4915208, stream);   // deg8_e + deg8_u + ctrs (contiguous)
    int convN = tierA ? (NENT*CC/4) : 0;
    int gh = (EE + NNZI + convN + 255)/256;
    k_hist<<<gh, 256, 0, stream>>>(head, irows, deg8_e, deg8_u, rank_e, rank_u,
                                   entity_emb, tierA ? ebf : nullptr);
    k_base2<<<(NENT+255)/256, 256, 0, stream>>>(deg8_e, deg8_u, rsdeg_e, rsdeg_u, ctrs);
    int gs = (EE + NNZI + 255)/256;
    k_scatter<<<gs, 256, 0, stream>>>(head, tail, etype, cate, irows, icols, ivals,
                                      rank_e, rank_u, deg8_e, deg8_u,
                                      rsdeg_e, rsdeg_u, epk, upk);

    // ---- latent path
    LatArgs a_c0 = {latent_emb, cW1, cb1, cW2, cb2, cWua, cbua, cWwa, cbwa, weight,
                    latn[0][0], nlat[0][0], P2b[0][0], q2b[0][0], R1_};
    LatArgs a_d0 = {latent_div, eW1, eb1, eW2, eb2, eWua, ebua, eWwa, ebwa, weight_d,
                    latn[1][0], nlat[1][0], P2b[1][0], q2b[1][0], R2_};
    k_lat2<<<2, 256, 0, stream>>>(a_c0, a_d0);
    LatArgs a_c1 = {latn[0][0], cW1+4096, cb1+64, cW2+4096, cb2+64, cWua+16, cbua+4,
                    cWwa+R1_*R1_, cbwa+R1_, weight,
                    latn[0][1], nlat[0][1], P2b[0][1], q2b[0][1], R1_};
    LatArgs a_d1 = {nlat[1][0], eW1+4096, eb1+64, eW2+4096, eb2+64, eWua+16, ebua+4,
                    eWwa+R2_*R2_, ebwa+R2_, weight_d,
                    latn[1][1], nlat[1][1], P2b[1][1], q2b[1][1], R2_};
    k_lat2<<<2, 256, 0, stream>>>(a_c1, a_d1);

    int ge = GE_, gu = GU_;
    if (tierA){
        // fused iter-0 (entity + user roles in one dispatch; both read only ebf + CSR)
        k_it0<<<ge + gu, 256, 0, stream>>>(ebf, weight, weight_d, rsdeg_e, epk, eA2,
            user_emb, rsdeg_u, upk,
            P2b[0][0], q2b[0][0], latn[0][0],
            P2b[1][0], q2b[1][0], latn[1][0], ou_c, ou_d);
        // fused iter-1 (entity + user roles; both read only eA2 + CSR; outputs disjoint)
        k_it1<<<ge + gu, 256, 0, stream>>>(eA2, entity_emb, weight, weight_d,
            rsdeg_e, epk, oe_c, oe_d,
            ou_c, ou_d, user_emb, rsdeg_u, upk,
            P2b[0][1], q2b[0][1], latn[0][1],
            P2b[1][1], q2b[1][1], latn[1][1]);
    } else {
        const float* wts[2] = {weight, weight_d};
        const int    Rs[2]  = {R1_, R2_};
        float* oes[2] = {oe_c, oe_d};
        float* ous[2] = {ou_c, ou_d};
        for (int br = 0; br < 2; br++){
            k_ent0<<<ge, 256, 0, stream>>>(entity_emb, wts[br], Rs[br], br, rsdeg_e, epk, eA);
            k_usr0<<<gu, 256, 0, stream>>>(user_emb, entity_emb, rsdeg_u, upk,
                P2b[br][0], q2b[br][0], latn[br][0], ous[br]);
            k_ent1f<<<ge, 256, 0, stream>>>(eA, entity_emb, wts[br], Rs[br], br, rsdeg_e, epk, oes[br]);
            k_usr1f<<<gu, 256, 0, stream>>>(ous[br], eA, user_emb, rsdeg_u, upk,
                P2b[br][1], q2b[br][1], latn[br][1]);
        }
    }

    // ---- distance correlations
    k_cor<<<2, 256, 0, stream>>>(latn[0][1], latent_div, nlat[1][0], nlat[1][1], out);
}